// Round 11
// baseline (1380.247 us; speedup 1.0000x reference)
//
#include <hip/hip_runtime.h>
#include <math.h>

// TGCN: B=16, T=12, N=1000, H=128, NL=2
#define BB 16
#define TT 12
#define NN 1000
#define HH 128
#define CC 129
#define NROW 16000
#define GR 160            // Gfull rows per b (0:x, 1..128:h^T, 129..159:zero)
#define KP 1024
#define CP2 160           // stage-2 K (c padded)
#define SPS 168           // sP stride (bf16)

// LDS map (BK=128): 2 staging buffers of 52KB (26 chunks x 2KB: 8 L + 18 G) = [0,106496).
// Post-K-loop overlays on the dead staging region (all mutually disjoint):
//   sP @0 [21504) ; sGT/sT @21504 ; sO @39936 ; sHB @57344.
// Persistent: sScal @106496 (2560) ; sSt @109056 (4096). SMEMB = 113152.
#define BUFSZ    53248
#define OFF_SGT  21504
#define OFF_SO   39936
#define OFF_SHB  57344
#define OFF_SCAL 106496
#define OFF_SST  109056
#define SMEMB    113152

typedef __attribute__((ext_vector_type(4))) float f32x4;
typedef __attribute__((ext_vector_type(8))) __bf16 bf16x8;

#define MFMA16(A, B, C) __builtin_amdgcn_mfma_f32_16x16x32_bf16((A), (B), (C), 0, 0, 0)

__device__ __forceinline__ float sigmoidf_(float x) { return 1.0f / (1.0f + expf(-x)); }

// ---------------- laplacian ----------------
__global__ void k_softmax(const float* __restrict__ adj, float* __restrict__ a) {
    int i = blockIdx.x;
    int t = threadIdx.x;
    __shared__ float red[256];
    float m = -1e30f;
    for (int j = t; j < NN; j += 256) m = fmaxf(m, adj[i * NN + j]);
    red[t] = m; __syncthreads();
    for (int s = 128; s > 0; s >>= 1) { if (t < s) red[t] = fmaxf(red[t], red[t + s]); __syncthreads(); }
    m = red[0]; __syncthreads();
    float sum = 0.f;
    for (int j = t; j < NN; j += 256) sum += expf(adj[i * NN + j] - m);
    red[t] = sum; __syncthreads();
    for (int s = 128; s > 0; s >>= 1) { if (t < s) red[t] += red[t + s]; __syncthreads(); }
    float inv = 1.0f / red[0];
    for (int j = t; j < NN; j += 256) a[i * NN + j] = expf(adj[i * NN + j] - m) * inv;
}

__global__ __launch_bounds__(256) void k_build_Lt(const float* __restrict__ a, __bf16* __restrict__ Lb) {
    __shared__ float s[64][65];
    int bi = blockIdx.x * 64;
    int bj = blockIdx.y * 64;
    int t = threadIdx.x;
    for (int q = t; q < 64 * 64; q += 256) {
        int r = q >> 6, c = q & 63;
        int jj = bj + r, ii = bi + c;
        s[r][c] = (jj < NN && ii < NN) ? a[jj * NN + ii] : 0.f;
    }
    __syncthreads();
    for (int q = t; q < 64 * 64; q += 256) {
        int r = q >> 6, c = q & 63;
        int ii = bi + r, jj = bj + c;
        if (ii < NN && jj < NN)
            Lb[(size_t)ii * KP + jj] = (__bf16)(0.5f * (s[c][r] + (ii == jj ? 1.0f : 0.0f)));
    }
}

// ---------------- one-time weight prep ----------------
__global__ void k_prep(const float* __restrict__ wih, const float* __restrict__ whh,
                       const float* __restrict__ proj_w, const float* __restrict__ ow1,
                       const float* __restrict__ ow2, const float* __restrict__ gc1_w,
                       const float* __restrict__ gc2_w,
                       __bf16* __restrict__ WihB, __bf16* __restrict__ WhhB,
                       __bf16* __restrict__ projB, __bf16* __restrict__ w1B,
                       __bf16* __restrict__ w2B, __bf16* __restrict__ W1t,
                       __bf16* __restrict__ W2t) {
    int idx = blockIdx.x * 256 + threadIdx.x;
    if (idx < 49152) { WihB[idx] = (__bf16)wih[idx]; return; }
    idx -= 49152;
    if (idx < 49152) { WhhB[idx] = (__bf16)whh[idx]; return; }
    idx -= 49152;
    if (idx < 16384) { projB[idx] = (__bf16)proj_w[idx]; return; }
    idx -= 16384;
    if (idx < 32768) { w1B[idx] = (__bf16)ow1[idx]; return; }
    idx -= 32768;
    if (idx < 32768) { w2B[idx] = (__bf16)ow2[idx]; return; }
    idx -= 32768;
    if (idx < 2 * 256 * CP2) {
        int l = idx / (256 * CP2); int r = idx % (256 * CP2); int o = r / CP2, c = r % CP2;
        W1t[idx] = (c < CC) ? (__bf16)gc1_w[((size_t)l * CC + c) * 256 + o] : (__bf16)0.f;
        return;
    }
    idx -= 2 * 256 * CP2;
    if (idx < 2 * 128 * CP2) {
        int l = idx / (128 * CP2); int r = idx % (128 * CP2); int o = r / CP2, c = r % CP2;
        W2t[idx] = (c < CC) ? (__bf16)gc2_w[((size_t)l * CC + c) * 128 + o] : (__bf16)0.f;
    }
}

// Gfull0 row0 = x at t=0
__global__ void k_prep_x(const float* __restrict__ inp, __bf16* __restrict__ G0) {
    int idx = blockIdx.x * 256 + threadIdx.x;
    if (idx >= BB * 1024) return;
    int b = idx >> 10, k = idx & 1023;
    G0[(size_t)b * GR * KP + k] = (k < NN) ? (__bf16)inp[(size_t)b * TT * NN + k] : (__bf16)0.f;
}

// ---------------- fused graph-conv + weight matmul + epilogue (+ GRU when STORE) -------
// 1024 threads = 16 waves. Stage-1: all 16 waves (wm = m-half, wcg = 8 c-groups {2,1x7}).
// K=1024 in 8 steps of 128; 2-buffer pipeline: stage(it+1) right after barrier(it-1),
// drain vmcnt(0) only at step end (loads fly under the whole compute phase).
// Stage-2: MODE0 all 16 waves; MODE1 waves 0-7. Epilogues verified r6/r8/r10.
#define GL16(SRC, DSTOFF)                                                            \
    __builtin_amdgcn_global_load_lds(                                                \
        (const __attribute__((address_space(1))) unsigned int*)(SRC),                \
        (__attribute__((address_space(3))) unsigned int*)(smem + (DSTOFF)), 16, 0, 0)

template<int MODE, int STORE>
__global__ __launch_bounds__(1024) void k_fused(
    const __bf16* __restrict__ Lb, const __bf16* __restrict__ Gf,
    const __bf16* __restrict__ Wt, const float* __restrict__ bias,
    __bf16* __restrict__ GB, float* __restrict__ u, float* __restrict__ h,
    const float* __restrict__ x_in, int xstride,
    const float* __restrict__ res_w, const float* __restrict__ res_b,
    const float* __restrict__ ln_g, const float* __restrict__ ln_b,
    float* __restrict__ x_out, __bf16* __restrict__ Gnext,
    __bf16* __restrict__ GhSelf,
    float* __restrict__ hg, __bf16* __restrict__ Hb,
    const __bf16* __restrict__ WihB, const __bf16* __restrict__ WhhB,
    const float* __restrict__ bih, const float* __restrict__ bhh,
    const float* __restrict__ inp, __bf16* __restrict__ xnextG, int tnext)
{
    __shared__ __align__(16) char smem[SMEMB];
    __bf16* sP   = (__bf16*)smem;                   // [64][168] overlay @0
    __bf16* sGT  = (__bf16*)(smem + OFF_SGT);       // MODE0 [256][72]
    __bf16* sT   = (__bf16*)(smem + OFF_SGT);       // MODE1 [128][72]
    __bf16* sO   = (__bf16*)(smem + OFF_SO);        // MODE1 [64][136]
    float*  sScal= (float*)(smem + OFF_SCAL);
    float*  sSt  = (float*)(smem + OFF_SST);

    int tid = threadIdx.x;
    int wg = blockIdx.x;
    int b = wg & 15;                 // b%8 == XCD id
    int m0 = (wg >> 4) * 64;
    int wave = tid >> 6, lane = tid & 63;
    int lr = lane & 15, lk = lane >> 4;
    int wm = wave >> 3;              // m-half
    int wcg = wave & 7;              // c-group
    int cgbase = (wcg == 0) ? 0 : (wcg + 1) * 16;   // {0,32,48,...,128}
    int NC = (wcg == 0) ? 2 : 1;

    if (MODE == 0) {
        if (tid < 256) sScal[tid] = bias[tid];
    } else if (tid < 128) {
        sScal[tid] = bias[tid];
        sScal[128 + tid] = res_w[tid];
        sScal[256 + tid] = res_b[tid];
        sScal[384 + tid] = ln_g[tid];
        sScal[512 + tid] = ln_b[tid];
    }

    size_t srowOff = (size_t)b * GR * KP;
    int rIn = lane >> 3;
    int cswz = ((lane & 7) ^ rIn) * 8;   // pre-swizzled source col (elems)

    // staging: 52 pieces of 1KB (chunk c = p>>1, k-half hf = p&1).
    // wave w -> pieces {w, w+16, w+32} (+ {w+48} for w<4).
    const __bf16* psrc[4];
    int pdst[4];
#pragma unroll
    for (int q = 0; q < 4; q++) {
        int p = wave + q * 16;
        if (p < 52) {
            int c = p >> 1, hf = p & 1;
            psrc[q] = (c < 8)
                ? Lb + (size_t)(m0 + c * 8 + rIn) * KP + hf * 64 + cswz
                : Gf + srowOff + (size_t)((c - 8) * 8 + rIn) * KP + hf * 64 + cswz;
            pdst[q] = c * 2048 + hf * 1024;
        } else { psrc[q] = nullptr; pdst[q] = 0; }
    }

#define STAGE(BUF, IT) {                                                     \
    _Pragma("unroll")                                                        \
    for (int q = 0; q < 4; q++)                                              \
        if (wave + q * 16 < 52)                                              \
            GL16(psrc[q] + (IT) * 128, (BUF) * BUFSZ + pdst[q]); }

    f32x4 acc[2][2];
#pragma unroll
    for (int i = 0; i < 2; i++)
#pragma unroll
        for (int j = 0; j < 2; j++) acc[i][j] = (f32x4){0.f, 0.f, 0.f, 0.f};

    STAGE(0, 0);
    __syncthreads();                 // drains tile0 loads + sScal writes
    int bc = 0;
    for (int it = 0; it < 8; ++it) {
        if (it < 7) STAGE(bc ^ 1, it + 1);   // buf bc^1 free: all waves done reading it (barrier)
        const char* bp = smem + bc * BUFSZ;
#pragma unroll
        for (int ks = 0; ks < 4; ks++) {
            int kb = (((ks & 1) * 64) + lk * 16) ^ ((lr & 7) << 4);
            int ph = (ks >> 1) * 1024;
            bf16x8 af[2];
#pragma unroll
            for (int mf = 0; mf < 2; mf++) {
                int chA = wm * 4 + mf * 2 + (lr >> 3);
                af[mf] = *(const bf16x8*)(bp + chA * 2048 + ph + (lr & 7) * 128 + kb);
            }
#pragma unroll
            for (int cf = 0; cf < 2; cf++) {
                if (cf < NC) {
                    int chB = 8 + (cgbase >> 3) + cf * 2 + (lr >> 3);
                    bf16x8 bfr = *(const bf16x8*)(bp + chB * 2048 + ph + (lr & 7) * 128 + kb);
                    acc[0][cf] = MFMA16(af[0], bfr, acc[0][cf]);
                    acc[1][cf] = MFMA16(af[1], bfr, acc[1][cf]);
                }
            }
        }
        if (it < 7) {
            asm volatile("s_waitcnt vmcnt(0)" ::: "memory");   // tile it+1 landed
            __builtin_amdgcn_s_barrier();
            __builtin_amdgcn_sched_barrier(0);
        }
        bc ^= 1;
    }
    __syncthreads();
#undef STAGE

    // P -> sP bf16 (overlay @0; staging dead after the syncthreads above)
#pragma unroll
    for (int mf = 0; mf < 2; mf++)
#pragma unroll
        for (int cf = 0; cf < 2; cf++) {
            if (cf < NC) {
#pragma unroll
                for (int i = 0; i < 4; i++)
                    sP[(wm * 32 + mf * 16 + lk * 4 + i) * SPS + cgbase + cf * 16 + lr] =
                        (__bf16)acc[mf][cf][i];
            }
        }
    for (int q = tid; q < 64 * 16; q += 1024) sP[(q >> 4) * SPS + 144 + (q & 15)] = (__bf16)0.f;
    __syncthreads();

    // Stage 2: MODE0 -> all 16 waves (one 16-col o-group each); MODE1 -> waves 0-7.
    int o0 = wave * 16;
    int j = o0 + lr;                 // MODE0: o in [0,256); MODE1: j in [0,128) for wave<8
    f32x4 accs[4];
#pragma unroll
    for (int i = 0; i < 4; i++) accs[i] = (f32x4){0.f, 0.f, 0.f, 0.f};
    if (MODE == 0 || wave < 8) {
#pragma unroll
        for (int kk2 = 0; kk2 < CP2; kk2 += 32) {
            bf16x8 pa[4];
#pragma unroll
            for (int mf2 = 0; mf2 < 4; mf2++)
                pa[mf2] = *(const bf16x8*)&sP[(mf2 * 16 + lr) * SPS + kk2 + lk * 8];
            bf16x8 wb = *(const bf16x8*)&Wt[(size_t)(o0 + lr) * CP2 + kk2 + lk * 8];
#pragma unroll
            for (int mf2 = 0; mf2 < 4; mf2++)
                accs[mf2] = MFMA16(pa[mf2], wb, accs[mf2]);
        }
    }

    if (MODE == 0) {
        if (tid < 8)
            *(bf16x8*)&GB[srowOff + m0 + tid * 8] = *(const bf16x8*)&Gf[srowOff + m0 + tid * 8];
        bool clean = (m0 + 64 <= 500);
        if (clean) {
            {
                int o = o0 + lr;
                float bv = sScal[o];
#pragma unroll
                for (int mf2 = 0; mf2 < 4; mf2++)
#pragma unroll
                    for (int i = 0; i < 4; i++)
                        sGT[o * 72 + mf2 * 16 + lk * 4 + i] = (__bf16)sigmoidf_(accs[mf2][i] + bv);
            }
            __syncthreads();
            for (int q = tid; q < 128 * 16; q += 1024) {
                int jj = q >> 4;
                int rnc = (q & 15) * 4;
                size_t gidx = srowOff + (size_t)(1 + jj) * KP + 2 * m0 + rnc * 2;
                bf16x8 hv = *(const bf16x8*)&Gf[gidx];
                bf16x8 rv;
#pragma unroll
                for (int e = 0; e < 8; e++) {
                    int rnl = rnc + (e >> 1);
                    int hi = e & 1;
                    float g = (float)sGT[(hi * 128 + jj) * 72 + rnl];
                    rv[e] = (__bf16)(g * (float)hv[e]);
                }
                *(bf16x8*)&GB[gidx] = rv;
            }
        } else {
            int o = o0 + lr;
            int jo = o & 127, hi = o >> 7;
            float bv = sScal[o];
#pragma unroll
            for (int mf2 = 0; mf2 < 4; mf2++)
#pragma unroll
                for (int i = 0; i < 4; i++) {
                    int m = m0 + mf2 * 16 + lk * 4 + i;
                    if (m >= NN) continue;
                    float g = sigmoidf_(accs[mf2][i] + bv);
                    if (m < 500) {
                        size_t gi = srowOff + (size_t)(1 + jo) * KP + 2 * m + hi;
                        GB[gi] = (__bf16)(g * (float)Gf[gi]);
                    } else {
                        u[((size_t)b * NN + 2 * (m - 500) + hi) * HH + jo] = g;
                    }
                }
        }
    } else {
        float hnv[4][4];
        float mu_[4][4], rs_[4][4];
        float xs_[4][4];
        if (wave < 8) {
            float s_[4][4], ss_[4][4];
#pragma unroll
            for (int a = 0; a < 4; a++)
#pragma unroll
                for (int i = 0; i < 4; i++) { s_[a][i] = 0.f; ss_[a][i] = 0.f; }
            float b2v = sScal[j], rwv = sScal[128 + j], rbv = sScal[256 + j];
#pragma unroll
            for (int mf2 = 0; mf2 < 4; mf2++) {
#pragma unroll
                for (int i = 0; i < 4; i++) {
                    int m = m0 + mf2 * 16 + lk * 4 + i;
                    int msafe = (m < NN) ? m : (NN - 1);
                    size_t ri = ((size_t)b * NN + msafe) * HH + j;
                    float cv = tanhf(accs[mf2][i] + b2v);
                    float uu = u[ri];
                    float hv = h[ri];
                    float hn = uu * hv + (1.f - uu) * cv;
                    if (m < NN) h[ri] = hn;
                    hnv[mf2][i] = hn;
                    float xv = (m < NN) ? x_in[(size_t)b * xstride + m] : 0.f;
                    float y = hn + xv * rwv + rbv;
                    accs[mf2][i] = y;
                    s_[mf2][i] += y; ss_[mf2][i] += y * y;
                }
            }
#pragma unroll
            for (int msk = 1; msk < 16; msk <<= 1)
#pragma unroll
                for (int a = 0; a < 4; a++)
#pragma unroll
                    for (int i = 0; i < 4; i++) {
                        s_[a][i] += __shfl_xor(s_[a][i], msk);
                        ss_[a][i] += __shfl_xor(ss_[a][i], msk);
                    }
            if (lr == 0) {
#pragma unroll
                for (int a = 0; a < 4; a++)
#pragma unroll
                    for (int i = 0; i < 4; i++) {
                        int ml = a * 16 + lk * 4 + i;
                        sSt[wave * 64 + ml] = s_[a][i];
                        sSt[512 + wave * 64 + ml] = ss_[a][i];
                    }
            }
        }
        __syncthreads();
        if (wave < 8) {
#pragma unroll
            for (int a = 0; a < 4; a++)
#pragma unroll
                for (int i = 0; i < 4; i++) {
                    int ml = a * 16 + lk * 4 + i;
                    float S = 0.f, SS = 0.f;
#pragma unroll
                    for (int w = 0; w < 8; w++) { S += sSt[w * 64 + ml]; SS += sSt[512 + w * 64 + ml]; }
                    float mu = S * (1.f / 128.f);
                    float var = SS * (1.f / 128.f) - mu * mu;
                    mu_[a][i] = mu;
                    rs_[a][i] = rsqrtf(var + 1e-5f);
                }
            float lg = sScal[384 + j], lb2 = sScal[512 + j];
#pragma unroll
            for (int mf2 = 0; mf2 < 4; mf2++)
#pragma unroll
                for (int i = 0; i < 4; i++) {
                    float ov = (accs[mf2][i] - mu_[mf2][i]) * rs_[mf2][i] * lg + lb2;
                    accs[mf2][i] = ov;
                    xs_[mf2][i] = ov;
                }
#pragma unroll
            for (int msk = 1; msk < 16; msk <<= 1)
#pragma unroll
                for (int a = 0; a < 4; a++)
#pragma unroll
                    for (int i = 0; i < 4; i++) xs_[a][i] += __shfl_xor(xs_[a][i], msk);
        }
        __syncthreads();
        if (wave < 8 && lr == 0) {
#pragma unroll
            for (int a = 0; a < 4; a++)
#pragma unroll
                for (int i = 0; i < 4; i++)
                    sSt[wave * 64 + a * 16 + lk * 4 + i] = xs_[a][i];
        }
        __syncthreads();
        if (wave == 0 && lr == 0) {
#pragma unroll
            for (int a = 0; a < 4; a++)
#pragma unroll
                for (int i = 0; i < 4; i++) {
                    int ml = a * 16 + lk * 4 + i;
                    int m = m0 + ml;
                    if (m < NN) {
                        float S = 0.f;
#pragma unroll
                        for (int w = 0; w < 8; w++) S += sSt[w * 64 + ml];
                        float xv = S * (1.f / 128.f);
                        if (x_out) x_out[(size_t)b * NN + m] = xv;
                        if (Gnext) Gnext[(size_t)b * GR * KP + m] = (__bf16)xv;
                    }
                }
        }
        if (wave < 8) {
#pragma unroll
            for (int mf2 = 0; mf2 < 4; mf2++)
#pragma unroll
                for (int i = 0; i < 4; i++)
                    sT[j * 72 + mf2 * 16 + lk * 4 + i] = (__bf16)hnv[mf2][i];
            if (STORE) {
#pragma unroll
                for (int mf2 = 0; mf2 < 4; mf2++)
#pragma unroll
                    for (int i = 0; i < 4; i++)
                        sO[(mf2 * 16 + lk * 4 + i) * 136 + j] = (__bf16)accs[mf2][i];
            }
        }
        if (STORE) {
            // stage previous-h (Hb) into LDS once: kills 8x redundant global reads
            int row = tid >> 4, c8 = (tid & 15) * 8;
            int m = m0 + row;
            size_t hrow = (size_t)b * NN + ((m < NN) ? m : (NN - 1));
            *(bf16x8*)(smem + OFF_SHB + (row * 136 + c8) * 2) =
                *(const bf16x8*)&Hb[hrow * HH + c8];
        }
        __syncthreads();
        for (int q = tid; q < 128 * 8; q += 1024) {
            int jj = q >> 3, mc = (q & 7) * 8;
            if (m0 + mc < NN)
                *(bf16x8*)&GhSelf[srowOff + (size_t)(1 + jj) * KP + m0 + mc] =
                    *(const bf16x8*)&sT[jj * 72 + mc];
        }
        if (STORE) {
            // ---- fused GRU step (wave-local j-slice: rows {j, 128+j, 256+j}) ----
            if (wave < 8) {
                float br  = bih[j] + bhh[j];
                float bz  = bih[128 + j] + bhh[128 + j];
                float bni = bih[256 + j], bnh = bhh[256 + j];
                const __bf16* wir = WihB + (size_t)j * HH;
                const __bf16* whr = WhhB + (size_t)j * HH;
                const __bf16* wiz = WihB + (size_t)(128 + j) * HH;
                const __bf16* whz = WhhB + (size_t)(128 + j) * HH;
                const __bf16* win = WihB + (size_t)(256 + j) * HH;
                const __bf16* whn = WhhB + (size_t)(256 + j) * HH;
#pragma unroll
                for (int mf = 0; mf < 4; mf++) {
                    f32x4 gr = (f32x4){0.f,0.f,0.f,0.f}, gz = gr, gni = gr, gnh = gr;
#pragma unroll
                    for (int kk = 0; kk < 128; kk += 32) {
                        bf16x8 xa = *(const bf16x8*)&sO[(mf * 16 + lr) * 136 + kk + lk * 8];
                        bf16x8 ha = *(const bf16x8*)(smem + OFF_SHB + ((mf * 16 + lr) * 136 + kk + lk * 8) * 2);
                        gr  = MFMA16(xa, *(const bf16x8*)(wir + kk + lk * 8), gr);
                        gr  = MFMA16(ha, *(const bf16x8*)(whr + kk + lk * 8), gr);
                        gz  = MFMA16(xa, *(const bf16x8*)(wiz + kk + lk * 8), gz);
                        gz  = MFMA16(ha, *(const bf16x8*)(whz + kk + lk * 8), gz);
                        gni = MFMA16(xa, *(const bf16x8*)(win + kk + lk * 8), gni);
                        gnh = MFMA16(ha, *(const bf16x8*)(whn + kk + lk * 8), gnh);
                    }
#pragma unroll
                    for (int i = 0; i < 4; i++) {
                        int m = m0 + mf * 16 + lk * 4 + i;
                        if (m >= NN) continue;
                        size_t ri = ((size_t)b * NN + m) * HH + j;
                        float hv = hg[ri];
                        float rg = sigmoidf_(gr[i] + br);
                        float zg = sigmoidf_(gz[i] + bz);
                        float ng = tanhf(gni[i] + bni + rg * (gnh[i] + bnh));
                        float hp = (1.f - zg) * ng + zg * hv;
                        hg[ri] = hp;
                        Hb[ri] = (__bf16)hp;
                    }
                }
            }
            if (tid < 64 && tnext < TT) {
                int n = m0 + tid;
                if (n < NN)
                    xnextG[srowOff + n] = (__bf16)inp[(size_t)b * TT * NN + tnext * NN + n];
            }
        }
    }
}
#undef GL16

// ---------------- head: proj -> relu MLP -> out, MFMA ----------------
__global__ __launch_bounds__(256) void k_head_mfma(const __bf16* __restrict__ Hb,
                                                   const __bf16* __restrict__ projB,
                                                   const float* __restrict__ pb,
                                                   const __bf16* __restrict__ w1B,
                                                   const float* __restrict__ b1,
                                                   const __bf16* __restrict__ w2B,
                                                   const float* __restrict__ b2,
                                                   float* __restrict__ out) {
    __shared__ __align__(16) __bf16 sH1[64 * 136];
    __shared__ __align__(16) __bf16 sH2[64 * 264];
    int tid = threadIdx.x;
    int r0 = blockIdx.x * 64;
    int wv = tid >> 6, lane = tid & 63;
    int lr = lane & 15, lk = lane >> 4;
    int arow = r0 + wv * 16 + lr;

    f32x4 a1[8];
#pragma unroll
    for (int i = 0; i < 8; i++) a1[i] = (f32x4){0.f, 0.f, 0.f, 0.f};
#pragma unroll
    for (int kk = 0; kk < 128; kk += 32) {
        bf16x8 xa = *(const bf16x8*)&Hb[(size_t)arow * HH + kk + lk * 8];
#pragma unroll
        for (int f = 0; f < 8; f++) {
            bf16x8 wb = *(const bf16x8*)&projB[(size_t)(f * 16 + lr) * HH + kk + lk * 8];
            a1[f] = MFMA16(xa, wb, a1[f]);
        }
    }
#pragma unroll
    for (int f = 0; f < 8; f++) {
        int j = f * 16 + lr;
        float bv = pb[j];
#pragma unroll
        for (int i = 0; i < 4; i++)
            sH1[(wv * 16 + lk * 4 + i) * 136 + j] = (__bf16)(a1[f][i] + bv);
    }
    __syncthreads();

    f32x4 a2[16];
#pragma unroll
    for (int i = 0; i < 16; i++) a2[i] = (f32x4){0.f, 0.f, 0.f, 0.f};
#pragma unroll
    for (int kk = 0; kk < 128; kk += 32) {
        bf16x8 pa = *(const bf16x8*)&sH1[(wv * 16 + lr) * 136 + kk + lk * 8];
#pragma unroll
        for (int f = 0; f < 16; f++) {
            bf16x8 wb = *(const bf16x8*)&w1B[(size_t)(f * 16 + lr) * HH + kk + lk * 8];
            a2[f] = MFMA16(pa, wb, a2[f]);
        }
    }
    __syncthreads();
#pragma unroll
    for (int f = 0; f < 16; f++) {
        int o = f * 16 + lr;
        float bv = b1[o];
#pragma unroll
        for (int i = 0; i < 4; i++)
            sH2[(wv * 16 + lk * 4 + i) * 264 + o] = (__bf16)fmaxf(a2[f][i] + bv, 0.f);
    }
    __syncthreads();

    f32x4 a3[8];
#pragma unroll
    for (int i = 0; i < 8; i++) a3[i] = (f32x4){0.f, 0.f, 0.f, 0.f};
#pragma unroll
    for (int kk = 0; kk < 256; kk += 32) {
        bf16x8 pa = *(const bf16x8*)&sH2[(wv * 16 + lr) * 264 + kk + lk * 8];
#pragma unroll
        for (int f = 0; f < 8; f++) {
            bf16x8 wb = *(const bf16x8*)&w2B[(size_t)(f * 16 + lr) * 256 + kk + lk * 8];
            a3[f] = MFMA16(pa, wb, a3[f]);
        }
    }
#pragma unroll
    for (int f = 0; f < 8; f++) {
        int j = f * 16 + lr;
        float bv = b2[j];
#pragma unroll
        for (int i = 0; i < 4; i++)
            out[(size_t)(r0 + wv * 16 + lk * 4 + i) * HH + j] = a3[f][i] + bv;
    }
}

extern "C" void kernel_launch(void* const* d_in, const int* in_sizes, int n_in,
                              void* d_out, int out_size, void* d_ws, size_t ws_size,
                              hipStream_t stream) {
    const float* inp    = (const float*)d_in[0];
    const float* adj    = (const float*)d_in[1];
    const float* gc1_w  = (const float*)d_in[2];
    const float* gc1_b  = (const float*)d_in[3];
    const float* gc2_w  = (const float*)d_in[4];
    const float* gc2_b  = (const float*)d_in[5];
    const float* ln_g   = (const float*)d_in[6];
    const float* ln_b   = (const float*)d_in[7];
    const float* res_w  = (const float*)d_in[8];
    const float* res_b  = (const float*)d_in[9];
    const float* wih    = (const float*)d_in[10];
    const float* whh    = (const float*)d_in[11];
    const float* bih    = (const float*)d_in[12];
    const float* bhh    = (const float*)d_in[13];
    const float* proj_w = (const float*)d_in[14];
    const float* proj_b = (const float*)d_in[15];
    const float* ow1    = (const float*)d_in[16];
    const float* ob1    = (const float*)d_in[17];
    const float* ow2    = (const float*)d_in[18];
    const float* ob2    = (const float*)d_in[19];
    float* out = (float*)d_out;

    char* ws = (char*)d_ws;
    size_t off = 0;
    __bf16* Lb     = (__bf16*)(ws + off); off += (size_t)KP * KP * 2;          // 2 MB
    __bf16* Gfull0 = (__bf16*)(ws + off); off += (size_t)BB * GR * KP * 2;     // 5 MB
    __bf16* Gfull1 = (__bf16*)(ws + off); off += (size_t)BB * GR * KP * 2;
    __bf16* GfullB = (__bf16*)(ws + off); off += (size_t)BB * GR * KP * 2;
    size_t zgrp1 = off;
    float* h0   = (float*)(ws + off);  off += (size_t)NROW * HH * 4;
    float* h1   = (float*)(ws + off);  off += (size_t)NROW * HH * 4;
    float* hg   = (float*)(ws + off);  off += (size_t)NROW * HH * 4;
    __bf16* Hb  = (__bf16*)(ws + off); off += (size_t)NROW * HH * 2;
    float* u    = (float*)(ws + off);  off += (size_t)NROW * HH * 4;
    float* xB   = (float*)(ws + off);  off += NROW * 4;
    __bf16* W1t = (__bf16*)(ws + off); off += (size_t)2 * 256 * CP2 * 2;
    __bf16* W2t = (__bf16*)(ws + off); off += (size_t)2 * 128 * CP2 * 2;
    __bf16* WihB= (__bf16*)(ws + off); off += 49152 * 2;
    __bf16* WhhB= (__bf16*)(ws + off); off += 49152 * 2;
    __bf16* projB=(__bf16*)(ws + off); off += 16384 * 2;
    __bf16* w1B = (__bf16*)(ws + off); off += 32768 * 2;
    __bf16* w2B = (__bf16*)(ws + off); off += 32768 * 2;
    float* a_sm = u;   // overlay: softmax scratch only used before u's first write

    hipMemsetAsync(Lb, 0, zgrp1, stream);                     // Lb + Gfull0/1/B
    hipMemsetAsync(h0, 0, (size_t)NROW * HH * 8, stream);     // h0, h1
    hipMemsetAsync(hg, 0, (size_t)NROW * HH * 6, stream);     // hg, Hb

    k_softmax<<<NN, 256, 0, stream>>>(adj, a_sm);
    k_build_Lt<<<dim3(16, 16), 256, 0, stream>>>(a_sm, Lb);
    k_prep<<<1184, 256, 0, stream>>>(wih, whh, proj_w, ow1, ow2, gc1_w, gc2_w,
                                     WihB, WhhB, projB, w1B, w2B, W1t, W2t);
    k_prep_x<<<64, 256, 0, stream>>>(inp, Gfull0);

    for (int t = 0; t < TT; t++) {
        const float* xs0 = inp + (size_t)t * NN;
        // layer 0
        k_fused<0, 0><<<256, 1024, 0, stream>>>(Lb, Gfull0, W1t, gc1_b, GfullB, u,
            nullptr, nullptr, 0, nullptr, nullptr, nullptr, nullptr,
            nullptr, nullptr, nullptr,
            nullptr, nullptr, nullptr, nullptr, nullptr, nullptr, nullptr, nullptr, 0);
        k_fused<1, 0><<<256, 1024, 0, stream>>>(Lb, GfullB, W2t, gc2_b, nullptr, u, h0,
            xs0, TT * NN, res_w, res_b, ln_g, ln_b,
            xB, Gfull1, Gfull0,
            nullptr, nullptr, nullptr, nullptr, nullptr, nullptr, nullptr, nullptr, 0);
        // layer 1
        k_fused<0, 0><<<256, 1024, 0, stream>>>(Lb, Gfull1, W1t + 256 * CP2, gc1_b + 256, GfullB, u,
            nullptr, nullptr, 0, nullptr, nullptr, nullptr, nullptr,
            nullptr, nullptr, nullptr,
            nullptr, nullptr, nullptr, nullptr, nullptr, nullptr, nullptr, nullptr, 0);
        k_fused<1, 1><<<256, 1024, 0, stream>>>(Lb, GfullB, W2t + 128 * CP2, gc2_b + 128, nullptr, u, h1,
            xB, NN, res_w, res_b, ln_g + 128, ln_b + 128,
            nullptr, nullptr, Gfull1,
            hg, Hb, WihB, WhhB, bih, bhh, inp, Gfull0, t + 1);
    }
    k_head_mfma<<<250, 256, 0, stream>>>(Hb, projB, proj_b, w1B, ob1, w2B, ob2, out);
}

// Round 12
// 1361.927 us; speedup vs baseline: 1.0135x; 1.0135x over previous
//
#include <hip/hip_runtime.h>
#include <math.h>

// TGCN: B=16, T=12, N=1000, H=128, NL=2
#define BB 16
#define TT 12
#define NN 1000
#define HH 128
#define CC 129
#define NROW 16000
#define GR 160            // Gfull rows per b (0:x, 1..128:h^T, 129..159:zero)
#define KP 1024
#define CP2 160           // stage-2 K (c padded)
#define SPS 168           // sP stride (bf16)

// m-tile = 32 rows, 512 blocks, 512 threads (8 waves), 2 blocks/CU.
// LDS: 3 staging buffers of 22KB (22 chunks x 1KB: 4 L + 18 G) = [0,67584).
// Overlays on dead staging: sP @0 (10752) ; sGT/sT @10752 ; sO @31232 ; sHB @39936.
// Persistent: sScal @67584 (2560) ; sSt @70144 (2048). SMEMB = 72192 -> 2 blocks/CU.
#define BUFSZ    22528
#define OFF_SGT  10752
#define OFF_SO   31232
#define OFF_SHB  39936
#define OFF_SCAL 67584
#define OFF_SST  70144
#define SMEMB    72192

typedef __attribute__((ext_vector_type(4))) float f32x4;
typedef __attribute__((ext_vector_type(8))) __bf16 bf16x8;

#define MFMA16(A, B, C) __builtin_amdgcn_mfma_f32_16x16x32_bf16((A), (B), (C), 0, 0, 0)

__device__ __forceinline__ float sigmoidf_(float x) { return 1.0f / (1.0f + expf(-x)); }

// ---------------- laplacian ----------------
__global__ void k_softmax(const float* __restrict__ adj, float* __restrict__ a) {
    int i = blockIdx.x;
    int t = threadIdx.x;
    __shared__ float red[256];
    float m = -1e30f;
    for (int j = t; j < NN; j += 256) m = fmaxf(m, adj[i * NN + j]);
    red[t] = m; __syncthreads();
    for (int s = 128; s > 0; s >>= 1) { if (t < s) red[t] = fmaxf(red[t], red[t + s]); __syncthreads(); }
    m = red[0]; __syncthreads();
    float sum = 0.f;
    for (int j = t; j < NN; j += 256) sum += expf(adj[i * NN + j] - m);
    red[t] = sum; __syncthreads();
    for (int s = 128; s > 0; s >>= 1) { if (t < s) red[t] += red[t + s]; __syncthreads(); }
    float inv = 1.0f / red[0];
    for (int j = t; j < NN; j += 256) a[i * NN + j] = expf(adj[i * NN + j] - m) * inv;
}

__global__ __launch_bounds__(256) void k_build_Lt(const float* __restrict__ a, __bf16* __restrict__ Lb) {
    __shared__ float s[64][65];
    int bi = blockIdx.x * 64;
    int bj = blockIdx.y * 64;
    int t = threadIdx.x;
    for (int q = t; q < 64 * 64; q += 256) {
        int r = q >> 6, c = q & 63;
        int jj = bj + r, ii = bi + c;
        s[r][c] = (jj < NN && ii < NN) ? a[jj * NN + ii] : 0.f;
    }
    __syncthreads();
    for (int q = t; q < 64 * 64; q += 256) {
        int r = q >> 6, c = q & 63;
        int ii = bi + r, jj = bj + c;
        if (ii < NN && jj < NN)
            Lb[(size_t)ii * KP + jj] = (__bf16)(0.5f * (s[c][r] + (ii == jj ? 1.0f : 0.0f)));
    }
}

// ---------------- one-time weight prep ----------------
__global__ void k_prep(const float* __restrict__ wih, const float* __restrict__ whh,
                       const float* __restrict__ proj_w, const float* __restrict__ ow1,
                       const float* __restrict__ ow2, const float* __restrict__ gc1_w,
                       const float* __restrict__ gc2_w,
                       __bf16* __restrict__ WihB, __bf16* __restrict__ WhhB,
                       __bf16* __restrict__ projB, __bf16* __restrict__ w1B,
                       __bf16* __restrict__ w2B, __bf16* __restrict__ W1t,
                       __bf16* __restrict__ W2t) {
    int idx = blockIdx.x * 256 + threadIdx.x;
    if (idx < 49152) { WihB[idx] = (__bf16)wih[idx]; return; }
    idx -= 49152;
    if (idx < 49152) { WhhB[idx] = (__bf16)whh[idx]; return; }
    idx -= 49152;
    if (idx < 16384) { projB[idx] = (__bf16)proj_w[idx]; return; }
    idx -= 16384;
    if (idx < 32768) { w1B[idx] = (__bf16)ow1[idx]; return; }
    idx -= 32768;
    if (idx < 32768) { w2B[idx] = (__bf16)ow2[idx]; return; }
    idx -= 32768;
    if (idx < 2 * 256 * CP2) {
        int l = idx / (256 * CP2); int r = idx % (256 * CP2); int o = r / CP2, c = r % CP2;
        W1t[idx] = (c < CC) ? (__bf16)gc1_w[((size_t)l * CC + c) * 256 + o] : (__bf16)0.f;
        return;
    }
    idx -= 2 * 256 * CP2;
    if (idx < 2 * 128 * CP2) {
        int l = idx / (128 * CP2); int r = idx % (128 * CP2); int o = r / CP2, c = r % CP2;
        W2t[idx] = (c < CC) ? (__bf16)gc2_w[((size_t)l * CC + c) * 128 + o] : (__bf16)0.f;
    }
}

// Gfull0 row0 = x at t=0
__global__ void k_prep_x(const float* __restrict__ inp, __bf16* __restrict__ G0) {
    int idx = blockIdx.x * 256 + threadIdx.x;
    if (idx >= BB * 1024) return;
    int b = idx >> 10, k = idx & 1023;
    G0[(size_t)b * GR * KP + k] = (k < NN) ? (__bf16)inp[(size_t)b * TT * NN + k] : (__bf16)0.f;
}

// ---------------- fused graph-conv + weight matmul + epilogue (+ GRU when STORE) -------
// 512 threads = 8 waves. Stage-1: wm = m-half (16 rows), wcg = 4 c-groups {3,2,2,2}.
// K=1024 in 16 steps of 64; 3-buffer pipeline, counted vmcnt (nld per wave), XOR-swizzle.
// Stage-2: MODE0 all 8 waves x 2 o-frags; MODE1 all 8 waves x 1. Epilogues verified r10.
#define GL16(SRC, DSTOFF)                                                            \
    __builtin_amdgcn_global_load_lds(                                                \
        (const __attribute__((address_space(1))) unsigned int*)(SRC),                \
        (__attribute__((address_space(3))) unsigned int*)(smem + (DSTOFF)), 16, 0, 0)

template<int MODE, int STORE>
__global__ __launch_bounds__(512) void k_fused(
    const __bf16* __restrict__ Lb, const __bf16* __restrict__ Gf,
    const __bf16* __restrict__ Wt, const float* __restrict__ bias,
    __bf16* __restrict__ GB, float* __restrict__ u, float* __restrict__ h,
    const float* __restrict__ x_in, int xstride,
    const float* __restrict__ res_w, const float* __restrict__ res_b,
    const float* __restrict__ ln_g, const float* __restrict__ ln_b,
    float* __restrict__ x_out, __bf16* __restrict__ Gnext,
    __bf16* __restrict__ GhSelf,
    float* __restrict__ hg, __bf16* __restrict__ Hb,
    const __bf16* __restrict__ WihB, const __bf16* __restrict__ WhhB,
    const float* __restrict__ bih, const float* __restrict__ bhh,
    const float* __restrict__ inp, __bf16* __restrict__ xnextG, int tnext)
{
    __shared__ __align__(16) char smem[SMEMB];
    __bf16* sP   = (__bf16*)smem;                   // [32][168] overlay @0
    __bf16* sGT  = (__bf16*)(smem + OFF_SGT);       // MODE0 [256][40]
    __bf16* sT   = (__bf16*)(smem + OFF_SGT);       // MODE1 [128][40]
    __bf16* sO   = (__bf16*)(smem + OFF_SO);        // MODE1 [32][136]
    float*  sScal= (float*)(smem + OFF_SCAL);
    float*  sSt  = (float*)(smem + OFF_SST);        // [2][8][32]

    int tid = threadIdx.x;
    int wg = blockIdx.x;
    int b = wg & 15;                 // wg%8 == b%8 -> XCD locality
    int m0 = (wg >> 4) * 32;
    int wave = tid >> 6, lane = tid & 63;
    int lr = lane & 15, lk = lane >> 4;
    int wm = wave >> 2;              // m-half (16 rows)
    int wcg = wave & 3;              // c-group
    int cgbase = (wcg == 0) ? 0 : (wcg * 2 + 1) * 16;   // {0,48,80,112}
    int NC = (wcg == 0) ? 3 : 2;

    if (MODE == 0) {
        if (tid < 256) sScal[tid] = bias[tid];
    } else if (tid < 128) {
        sScal[tid] = bias[tid];
        sScal[128 + tid] = res_w[tid];
        sScal[256 + tid] = res_b[tid];
        sScal[384 + tid] = ln_g[tid];
        sScal[512 + tid] = ln_b[tid];
    }

    size_t srowOff = (size_t)b * GR * KP;
    int rIn = lane >> 3;
    int cswz = ((lane & 7) ^ rIn) * 8;   // pre-swizzled source col (elems)

    // staging: 22 chunks of 1KB (4 L + 18 G); wave w -> {w, w+8, w+16 if <22}.
    int nld = (wave < 6) ? 3 : 2;
    const __bf16* psrc[3];
    int pdst[3];
#pragma unroll
    for (int q = 0; q < 3; q++) {
        int c = wave + q * 8;
        if (c < 22) {
            psrc[q] = (c < 4)
                ? Lb + (size_t)(m0 + c * 8 + rIn) * KP + cswz
                : Gf + srowOff + (size_t)((c - 4) * 8 + rIn) * KP + cswz;
            pdst[q] = c * 1024;
        } else { psrc[q] = nullptr; pdst[q] = 0; }
    }

#define STAGE(BUF, IT) {                                                     \
    _Pragma("unroll")                                                        \
    for (int q = 0; q < 3; q++)                                              \
        if (wave + q * 8 < 22)                                               \
            GL16(psrc[q] + (IT) * 64, (BUF) * BUFSZ + pdst[q]); }

    f32x4 acc[3];
#pragma unroll
    for (int j = 0; j < 3; j++) acc[j] = (f32x4){0.f, 0.f, 0.f, 0.f};

    STAGE(0, 0);
    __syncthreads();                 // drains tile0 + sScal
    STAGE(1, 1);
    int bc = 0;
    for (int it = 0; it < 16; ++it) {
        if (it == 15) asm volatile("s_waitcnt vmcnt(0)" ::: "memory");
        else if (nld == 3) asm volatile("s_waitcnt vmcnt(3)" ::: "memory");
        else               asm volatile("s_waitcnt vmcnt(2)" ::: "memory");
        __builtin_amdgcn_s_barrier();
        __builtin_amdgcn_sched_barrier(0);
        const char* bp = smem + bc * BUFSZ;
#pragma unroll
        for (int ks = 0; ks < 2; ks++) {
            int kb = (ks * 64 + lk * 16) ^ ((lr & 7) << 4);
            int chA = wm * 2 + (lr >> 3);
            bf16x8 af = *(const bf16x8*)(bp + chA * 1024 + (lr & 7) * 128 + kb);
#pragma unroll
            for (int cf = 0; cf < 3; cf++) {
                if (cf < NC) {
                    int chB = 4 + (cgbase >> 3) + cf * 2 + (lr >> 3);
                    bf16x8 bfr = *(const bf16x8*)(bp + chB * 1024 + (lr & 7) * 128 + kb);
                    acc[cf] = MFMA16(af, bfr, acc[cf]);
                }
            }
        }
        if (it < 14) { int bs = (it + 2) % 3; STAGE(bs, it + 2); }
        bc = (bc == 2) ? 0 : bc + 1;
    }
    __syncthreads();
#undef STAGE

    // P -> sP bf16 (overlay @0; staging dead)
#pragma unroll
    for (int cf = 0; cf < 3; cf++) {
        if (cf < NC) {
#pragma unroll
            for (int i = 0; i < 4; i++)
                sP[(wm * 16 + lk * 4 + i) * SPS + cgbase + cf * 16 + lr] = (__bf16)acc[cf][i];
        }
    }
    for (int q = tid; q < 32 * 16; q += 512) sP[(q >> 4) * SPS + 144 + (q & 15)] = (__bf16)0.f;
    __syncthreads();

    // Stage 2: MODE0 -> 8 waves x 2 o-frags (o0=wave*32); MODE1 -> 8 waves x 1 (o0=wave*16).
    constexpr int NOF = (MODE == 0) ? 2 : 1;
    int o0 = wave * NOF * 16;
    int j = o0 + lr;                 // MODE1 j in [0,128)
    f32x4 accs[2][NOF];
#pragma unroll
    for (int i = 0; i < 2; i++)
#pragma unroll
        for (int jj = 0; jj < NOF; jj++) accs[i][jj] = (f32x4){0.f, 0.f, 0.f, 0.f};
#pragma unroll
    for (int kk2 = 0; kk2 < CP2; kk2 += 32) {
        bf16x8 pa[2];
#pragma unroll
        for (int mf2 = 0; mf2 < 2; mf2++)
            pa[mf2] = *(const bf16x8*)&sP[(mf2 * 16 + lr) * SPS + kk2 + lk * 8];
#pragma unroll
        for (int of = 0; of < NOF; of++) {
            bf16x8 wb = *(const bf16x8*)&Wt[(size_t)(o0 + of * 16 + lr) * CP2 + kk2 + lk * 8];
#pragma unroll
            for (int mf2 = 0; mf2 < 2; mf2++)
                accs[mf2][of] = MFMA16(pa[mf2], wb, accs[mf2][of]);
        }
    }

    if (MODE == 0) {
        if (tid < 4)
            *(bf16x8*)&GB[srowOff + m0 + tid * 8] = *(const bf16x8*)&Gf[srowOff + m0 + tid * 8];
        bool clean = (m0 + 32 <= 500);
        if (clean) {
#pragma unroll
            for (int of = 0; of < NOF; of++) {
                int o = o0 + of * 16 + lr;
                float bv = sScal[o];
#pragma unroll
                for (int mf2 = 0; mf2 < 2; mf2++)
#pragma unroll
                    for (int i = 0; i < 4; i++)
                        sGT[o * 40 + mf2 * 16 + lk * 4 + i] = (__bf16)sigmoidf_(accs[mf2][of][i] + bv);
            }
            __syncthreads();
            for (int q = tid; q < 128 * 8; q += 512) {
                int jj = q >> 3;
                int rnc = (q & 7) * 4;
                size_t gidx = srowOff + (size_t)(1 + jj) * KP + 2 * m0 + rnc * 2;
                bf16x8 hv = *(const bf16x8*)&Gf[gidx];
                bf16x8 rv;
#pragma unroll
                for (int e = 0; e < 8; e++) {
                    int rnl = rnc + (e >> 1);
                    int hi = e & 1;
                    float g = (float)sGT[(hi * 128 + jj) * 40 + rnl];
                    rv[e] = (__bf16)(g * (float)hv[e]);
                }
                *(bf16x8*)&GB[gidx] = rv;
            }
        } else {
#pragma unroll
            for (int of = 0; of < NOF; of++) {
                int o = o0 + of * 16 + lr;
                int jo = o & 127, hi = o >> 7;
                float bv = sScal[o];
#pragma unroll
                for (int mf2 = 0; mf2 < 2; mf2++)
#pragma unroll
                    for (int i = 0; i < 4; i++) {
                        int m = m0 + mf2 * 16 + lk * 4 + i;
                        if (m >= NN) continue;
                        float g = sigmoidf_(accs[mf2][of][i] + bv);
                        if (m < 500) {
                            size_t gi = srowOff + (size_t)(1 + jo) * KP + 2 * m + hi;
                            GB[gi] = (__bf16)(g * (float)Gf[gi]);
                        } else {
                            u[((size_t)b * NN + 2 * (m - 500) + hi) * HH + jo] = g;
                        }
                    }
            }
        }
    } else {
        float hnv[2][4];
        float mu_[2][4], rs_[2][4];
        float xs_[2][4];
        {
            float s_[2][4], ss_[2][4];
#pragma unroll
            for (int a = 0; a < 2; a++)
#pragma unroll
                for (int i = 0; i < 4; i++) { s_[a][i] = 0.f; ss_[a][i] = 0.f; }
            float b2v = sScal[j], rwv = sScal[128 + j], rbv = sScal[256 + j];
#pragma unroll
            for (int mf2 = 0; mf2 < 2; mf2++) {
#pragma unroll
                for (int i = 0; i < 4; i++) {
                    int m = m0 + mf2 * 16 + lk * 4 + i;
                    int msafe = (m < NN) ? m : (NN - 1);
                    size_t ri = ((size_t)b * NN + msafe) * HH + j;
                    float cv = tanhf(accs[mf2][0][i] + b2v);
                    float uu = u[ri];
                    float hv = h[ri];
                    float hn = uu * hv + (1.f - uu) * cv;
                    if (m < NN) h[ri] = hn;
                    hnv[mf2][i] = hn;
                    float xv = (m < NN) ? x_in[(size_t)b * xstride + m] : 0.f;
                    float y = hn + xv * rwv + rbv;
                    accs[mf2][0][i] = y;
                    s_[mf2][i] += y; ss_[mf2][i] += y * y;
                }
            }
#pragma unroll
            for (int msk = 1; msk < 16; msk <<= 1)
#pragma unroll
                for (int a = 0; a < 2; a++)
#pragma unroll
                    for (int i = 0; i < 4; i++) {
                        s_[a][i] += __shfl_xor(s_[a][i], msk);
                        ss_[a][i] += __shfl_xor(ss_[a][i], msk);
                    }
            if (lr == 0) {
#pragma unroll
                for (int a = 0; a < 2; a++)
#pragma unroll
                    for (int i = 0; i < 4; i++) {
                        int ml = a * 16 + lk * 4 + i;
                        sSt[wave * 32 + ml] = s_[a][i];
                        sSt[256 + wave * 32 + ml] = ss_[a][i];
                    }
            }
        }
        __syncthreads();
        {
#pragma unroll
            for (int a = 0; a < 2; a++)
#pragma unroll
                for (int i = 0; i < 4; i++) {
                    int ml = a * 16 + lk * 4 + i;
                    float S = 0.f, SS = 0.f;
#pragma unroll
                    for (int w = 0; w < 8; w++) { S += sSt[w * 32 + ml]; SS += sSt[256 + w * 32 + ml]; }
                    float mu = S * (1.f / 128.f);
                    float var = SS * (1.f / 128.f) - mu * mu;
                    mu_[a][i] = mu;
                    rs_[a][i] = rsqrtf(var + 1e-5f);
                }
            float lg = sScal[384 + j], lb2 = sScal[512 + j];
#pragma unroll
            for (int mf2 = 0; mf2 < 2; mf2++)
#pragma unroll
                for (int i = 0; i < 4; i++) {
                    float ov = (accs[mf2][0][i] - mu_[mf2][i]) * rs_[mf2][i] * lg + lb2;
                    accs[mf2][0][i] = ov;
                    xs_[mf2][i] = ov;
                }
#pragma unroll
            for (int msk = 1; msk < 16; msk <<= 1)
#pragma unroll
                for (int a = 0; a < 2; a++)
#pragma unroll
                    for (int i = 0; i < 4; i++) xs_[a][i] += __shfl_xor(xs_[a][i], msk);
        }
        __syncthreads();
        if (lr == 0) {
#pragma unroll
            for (int a = 0; a < 2; a++)
#pragma unroll
                for (int i = 0; i < 4; i++)
                    sSt[wave * 32 + a * 16 + lk * 4 + i] = xs_[a][i];
        }
        __syncthreads();
        if (wave == 0 && lr == 0) {
#pragma unroll
            for (int a = 0; a < 2; a++)
#pragma unroll
                for (int i = 0; i < 4; i++) {
                    int ml = a * 16 + lk * 4 + i;
                    int m = m0 + ml;
                    if (m < NN) {
                        float S = 0.f;
#pragma unroll
                        for (int w = 0; w < 8; w++) S += sSt[w * 32 + ml];
                        float xv = S * (1.f / 128.f);
                        if (x_out) x_out[(size_t)b * NN + m] = xv;
                        if (Gnext) Gnext[(size_t)b * GR * KP + m] = (__bf16)xv;
                    }
                }
        }
        {
#pragma unroll
            for (int mf2 = 0; mf2 < 2; mf2++)
#pragma unroll
                for (int i = 0; i < 4; i++)
                    sT[j * 40 + mf2 * 16 + lk * 4 + i] = (__bf16)hnv[mf2][i];
            if (STORE) {
#pragma unroll
                for (int mf2 = 0; mf2 < 2; mf2++)
#pragma unroll
                    for (int i = 0; i < 4; i++)
                        sO[(mf2 * 16 + lk * 4 + i) * 136 + j] = (__bf16)accs[mf2][0][i];
            }
        }
        if (STORE) {
            // stage previous-h (Hb) into LDS once (32 rows x 128 cols bf16)
            int row = tid >> 4, c8 = (tid & 15) * 8;
            int m = m0 + row;
            size_t hrow = (size_t)b * NN + ((m < NN) ? m : (NN - 1));
            *(bf16x8*)(smem + OFF_SHB + (row * 136 + c8) * 2) =
                *(const bf16x8*)&Hb[hrow * HH + c8];
        }
        __syncthreads();
        {
            int q = tid;   // 128 j x 4 chunks = 512 = blockDim
            int jj = q >> 2, mc = (q & 3) * 8;
            if (m0 + mc < NN)
                *(bf16x8*)&GhSelf[srowOff + (size_t)(1 + jj) * KP + m0 + mc] =
                    *(const bf16x8*)&sT[jj * 40 + mc];
        }
        if (STORE) {
            // ---- fused GRU step (wave-local j-slice: rows {j, 128+j, 256+j}) ----
            {
                float br  = bih[j] + bhh[j];
                float bz  = bih[128 + j] + bhh[128 + j];
                float bni = bih[256 + j], bnh = bhh[256 + j];
                const __bf16* wir = WihB + (size_t)j * HH;
                const __bf16* whr = WhhB + (size_t)j * HH;
                const __bf16* wiz = WihB + (size_t)(128 + j) * HH;
                const __bf16* whz = WhhB + (size_t)(128 + j) * HH;
                const __bf16* win = WihB + (size_t)(256 + j) * HH;
                const __bf16* whn = WhhB + (size_t)(256 + j) * HH;
#pragma unroll
                for (int mf = 0; mf < 2; mf++) {
                    f32x4 gr = (f32x4){0.f,0.f,0.f,0.f}, gz = gr, gni = gr, gnh = gr;
#pragma unroll
                    for (int kk = 0; kk < 128; kk += 32) {
                        bf16x8 xa = *(const bf16x8*)&sO[(mf * 16 + lr) * 136 + kk + lk * 8];
                        bf16x8 ha = *(const bf16x8*)(smem + OFF_SHB + ((mf * 16 + lr) * 136 + kk + lk * 8) * 2);
                        gr  = MFMA16(xa, *(const bf16x8*)(wir + kk + lk * 8), gr);
                        gr  = MFMA16(ha, *(const bf16x8*)(whr + kk + lk * 8), gr);
                        gz  = MFMA16(xa, *(const bf16x8*)(wiz + kk + lk * 8), gz);
                        gz  = MFMA16(ha, *(const bf16x8*)(whz + kk + lk * 8), gz);
                        gni = MFMA16(xa, *(const bf16x8*)(win + kk + lk * 8), gni);
                        gnh = MFMA16(ha, *(const bf16x8*)(whn + kk + lk * 8), gnh);
                    }
#pragma unroll
                    for (int i = 0; i < 4; i++) {
                        int m = m0 + mf * 16 + lk * 4 + i;
                        if (m >= NN) continue;
                        size_t ri = ((size_t)b * NN + m) * HH + j;
                        float hv = hg[ri];
                        float rg = sigmoidf_(gr[i] + br);
                        float zg = sigmoidf_(gz[i] + bz);
                        float ng = tanhf(gni[i] + bni + rg * (gnh[i] + bnh));
                        float hp = (1.f - zg) * ng + zg * hv;
                        hg[ri] = hp;
                        Hb[ri] = (__bf16)hp;
                    }
                }
            }
            if (tid < 32 && tnext < TT) {
                int n = m0 + tid;
                if (n < NN)
                    xnextG[srowOff + n] = (__bf16)inp[(size_t)b * TT * NN + tnext * NN + n];
            }
        }
    }
}
#undef GL16

// ---------------- head: proj -> relu MLP -> out, MFMA ----------------
__global__ __launch_bounds__(256) void k_head_mfma(const __bf16* __restrict__ Hb,
                                                   const __bf16* __restrict__ projB,
                                                   const float* __restrict__ pb,
                                                   const __bf16* __restrict__ w1B,
                                                   const float* __restrict__ b1,
                                                   const __bf16* __restrict__ w2B,
                                                   const float* __restrict__ b2,
                                                   float* __restrict__ out) {
    __shared__ __align__(16) __bf16 sH1[64 * 136];
    __shared__ __align__(16) __bf16 sH2[64 * 264];
    int tid = threadIdx.x;
    int r0 = blockIdx.x * 64;
    int wv = tid >> 6, lane = tid & 63;
    int lr = lane & 15, lk = lane >> 4;
    int arow = r0 + wv * 16 + lr;

    f32x4 a1[8];
#pragma unroll
    for (int i = 0; i < 8; i++) a1[i] = (f32x4){0.f, 0.f, 0.f, 0.f};
#pragma unroll
    for (int kk = 0; kk < 128; kk += 32) {
        bf16x8 xa = *(const bf16x8*)&Hb[(size_t)arow * HH + kk + lk * 8];
#pragma unroll
        for (int f = 0; f < 8; f++) {
            bf16x8 wb = *(const bf16x8*)&projB[(size_t)(f * 16 + lr) * HH + kk + lk * 8];
            a1[f] = MFMA16(xa, wb, a1[f]);
        }
    }
#pragma unroll
    for (int f = 0; f < 8; f++) {
        int j = f * 16 + lr;
        float bv = pb[j];
#pragma unroll
        for (int i = 0; i < 4; i++)
            sH1[(wv * 16 + lk * 4 + i) * 136 + j] = (__bf16)(a1[f][i] + bv);
    }
    __syncthreads();

    f32x4 a2[16];
#pragma unroll
    for (int i = 0; i < 16; i++) a2[i] = (f32x4){0.f, 0.f, 0.f, 0.f};
#pragma unroll
    for (int kk = 0; kk < 128; kk += 32) {
        bf16x8 pa = *(const bf16x8*)&sH1[(wv * 16 + lr) * 136 + kk + lk * 8];
#pragma unroll
        for (int f = 0; f < 16; f++) {
            bf16x8 wb = *(const bf16x8*)&w1B[(size_t)(f * 16 + lr) * HH + kk + lk * 8];
            a2[f] = MFMA16(pa, wb, a2[f]);
        }
    }
    __syncthreads();
#pragma unroll
    for (int f = 0; f < 16; f++) {
        int o = f * 16 + lr;
        float bv = b1[o];
#pragma unroll
        for (int i = 0; i < 4; i++)
            sH2[(wv * 16 + lk * 4 + i) * 264 + o] = (__bf16)fmaxf(a2[f][i] + bv, 0.f);
    }
    __syncthreads();

    f32x4 a3[8];
#pragma unroll
    for (int i = 0; i < 8; i++) a3[i] = (f32x4){0.f, 0.f, 0.f, 0.f};
#pragma unroll
    for (int kk = 0; kk < 256; kk += 32) {
        bf16x8 pa = *(const bf16x8*)&sH2[(wv * 16 + lr) * 264 + kk + lk * 8];
#pragma unroll
        for (int f = 0; f < 8; f++) {
            bf16x8 wb = *(const bf16x8*)&w2B[(size_t)(f * 16 + lr) * 256 + kk + lk * 8];
            a3[f] = MFMA16(pa, wb, a3[f]);
        }
    }
#pragma unroll
    for (int f = 0; f < 8; f++) {
        int j = f * 16 + lr;
        float bv = b2[j];
#pragma unroll
        for (int i = 0; i < 4; i++)
            out[(size_t)(r0 + wv * 16 + lk * 4 + i) * HH + j] = a3[f][i] + bv;
    }
}

extern "C" void kernel_launch(void* const* d_in, const int* in_sizes, int n_in,
                              void* d_out, int out_size, void* d_ws, size_t ws_size,
                              hipStream_t stream) {
    const float* inp    = (const float*)d_in[0];
    const float* adj    = (const float*)d_in[1];
    const float* gc1_w  = (const float*)d_in[2];
    const float* gc1_b  = (const float*)d_in[3];
    const float* gc2_w  = (const float*)d_in[4];
    const float* gc2_b  = (const float*)d_in[5];
    const float* ln_g   = (const float*)d_in[6];
    const float* ln_b   = (const float*)d_in[7];
    const float* res_w  = (const float*)d_in[8];
    const float* res_b  = (const float*)d_in[9];
    const float* wih    = (const float*)d_in[10];
    const float* whh    = (const float*)d_in[11];
    const float* bih    = (const float*)d_in[12];
    const float* bhh    = (const float*)d_in[13];
    const float* proj_w = (const float*)d_in[14];
    const float* proj_b = (const float*)d_in[15];
    const float* ow1    = (const float*)d_in[16];
    const float* ob1    = (const float*)d_in[17];
    const float* ow2    = (const float*)d_in[18];
    const float* ob2    = (const float*)d_in[19];
    float* out = (float*)d_out;

    char* ws = (char*)d_ws;
    size_t off = 0;
    __bf16* Lb     = (__bf16*)(ws + off); off += (size_t)KP * KP * 2;          // 2 MB
    __bf16* Gfull0 = (__bf16*)(ws + off); off += (size_t)BB * GR * KP * 2;     // 5 MB
    __bf16* Gfull1 = (__bf16*)(ws + off); off += (size_t)BB * GR * KP * 2;
    __bf16* GfullB = (__bf16*)(ws + off); off += (size_t)BB * GR * KP * 2;
    size_t zgrp1 = off;
    float* h0   = (float*)(ws + off);  off += (size_t)NROW * HH * 4;
    float* h1   = (float*)(ws + off);  off += (size_t)NROW * HH * 4;
    float* hg   = (float*)(ws + off);  off += (size_t)NROW * HH * 4;
    __bf16* Hb  = (__bf16*)(ws + off); off += (size_t)NROW * HH * 2;
    float* u    = (float*)(ws + off);  off += (size_t)NROW * HH * 4;
    float* xB   = (float*)(ws + off);  off += NROW * 4;
    __bf16* W1t = (__bf16*)(ws + off); off += (size_t)2 * 256 * CP2 * 2;
    __bf16* W2t = (__bf16*)(ws + off); off += (size_t)2 * 128 * CP2 * 2;
    __bf16* WihB= (__bf16*)(ws + off); off += 49152 * 2;
    __bf16* WhhB= (__bf16*)(ws + off); off += 49152 * 2;
    __bf16* projB=(__bf16*)(ws + off); off += 16384 * 2;
    __bf16* w1B = (__bf16*)(ws + off); off += 32768 * 2;
    __bf16* w2B = (__bf16*)(ws + off); off += 32768 * 2;
    float* a_sm = u;   // overlay: softmax scratch only used before u's first write

    hipMemsetAsync(Lb, 0, zgrp1, stream);                     // Lb + Gfull0/1/B
    hipMemsetAsync(h0, 0, (size_t)NROW * HH * 8, stream);     // h0, h1
    hipMemsetAsync(hg, 0, (size_t)NROW * HH * 6, stream);     // hg, Hb

    k_softmax<<<NN, 256, 0, stream>>>(adj, a_sm);
    k_build_Lt<<<dim3(16, 16), 256, 0, stream>>>(a_sm, Lb);
    k_prep<<<1184, 256, 0, stream>>>(wih, whh, proj_w, ow1, ow2, gc1_w, gc2_w,
                                     WihB, WhhB, projB, w1B, w2B, W1t, W2t);
    k_prep_x<<<64, 256, 0, stream>>>(inp, Gfull0);

    for (int t = 0; t < TT; t++) {
        const float* xs0 = inp + (size_t)t * NN;
        // layer 0
        k_fused<0, 0><<<512, 512, 0, stream>>>(Lb, Gfull0, W1t, gc1_b, GfullB, u,
            nullptr, nullptr, 0, nullptr, nullptr, nullptr, nullptr,
            nullptr, nullptr, nullptr,
            nullptr, nullptr, nullptr, nullptr, nullptr, nullptr, nullptr, nullptr, 0);
        k_fused<1, 0><<<512, 512, 0, stream>>>(Lb, GfullB, W2t, gc2_b, nullptr, u, h0,
            xs0, TT * NN, res_w, res_b, ln_g, ln_b,
            xB, Gfull1, Gfull0,
            nullptr, nullptr, nullptr, nullptr, nullptr, nullptr, nullptr, nullptr, 0);
        // layer 1
        k_fused<0, 0><<<512, 512, 0, stream>>>(Lb, Gfull1, W1t + 256 * CP2, gc1_b + 256, GfullB, u,
            nullptr, nullptr, 0, nullptr, nullptr, nullptr, nullptr,
            nullptr, nullptr, nullptr,
            nullptr, nullptr, nullptr, nullptr, nullptr, nullptr, nullptr, nullptr, 0);
        k_fused<1, 1><<<512, 512, 0, stream>>>(Lb, GfullB, W2t + 128 * CP2, gc2_b + 128, nullptr, u, h1,
            xB, NN, res_w, res_b, ln_g + 128, ln_b + 128,
            nullptr, nullptr, Gfull1,
            hg, Hb, WihB, WhhB, bih, bhh, inp, Gfull0, t + 1);
    }
    k_head_mfma<<<250, 256, 0, stream>>>(Hb, projB, proj_b, w1B, ob1, w2B, ob2, out);
}

// Round 13
// 1318.803 us; speedup vs baseline: 1.0466x; 1.0327x over previous
//
#include <hip/hip_runtime.h>
#include <math.h>

// TGCN: B=16, T=12, N=1000, H=128, NL=2
#define BB 16
#define TT 12
#define NN 1000
#define HH 128
#define CC 129
#define NROW 16000
#define GR 160            // Gfull rows per b (0:x, 1..128:h^T, 129..159:zero)
#define KP 1024
#define CP2 160           // stage-2 K (c padded)
#define SPS 168           // sP stride (bf16)

// m-tile = 32 rows, 512 blocks, 512 threads (8 waves), 2 blocks/CU.
// LDS: 3 staging buffers of 22KB (22 chunks x 1KB: 4 L + 18 G) = [0,67584).
// Overlays on dead staging: sP @0 (10752) ; sGT/sT @10752 ; sO @31232 ; sHB @39936.
// Persistent: sScal @67584 (2560) ; sSt @70144 (2048). SMEMB = 72192 -> 2 blocks/CU.
#define BUFSZ    22528
#define OFF_SGT  10752
#define OFF_SO   31232
#define OFF_SHB  39936
#define OFF_SCAL 67584
#define OFF_SST  70144
#define SMEMB    72192

typedef __attribute__((ext_vector_type(4))) float f32x4;
typedef __attribute__((ext_vector_type(8))) __bf16 bf16x8;

#define MFMA16(A, B, C) __builtin_amdgcn_mfma_f32_16x16x32_bf16((A), (B), (C), 0, 0, 0)

__device__ __forceinline__ float sigmoidf_(float x) { return 1.0f / (1.0f + expf(-x)); }

// ---------------- laplacian ----------------
__global__ void k_softmax(const float* __restrict__ adj, float* __restrict__ a) {
    int i = blockIdx.x;
    int t = threadIdx.x;
    __shared__ float red[256];
    float m = -1e30f;
    for (int j = t; j < NN; j += 256) m = fmaxf(m, adj[i * NN + j]);
    red[t] = m; __syncthreads();
    for (int s = 128; s > 0; s >>= 1) { if (t < s) red[t] = fmaxf(red[t], red[t + s]); __syncthreads(); }
    m = red[0]; __syncthreads();
    float sum = 0.f;
    for (int j = t; j < NN; j += 256) sum += expf(adj[i * NN + j] - m);
    red[t] = sum; __syncthreads();
    for (int s = 128; s > 0; s >>= 1) { if (t < s) red[t] += red[t + s]; __syncthreads(); }
    float inv = 1.0f / red[0];
    for (int j = t; j < NN; j += 256) a[i * NN + j] = expf(adj[i * NN + j] - m) * inv;
}

__global__ __launch_bounds__(256) void k_build_Lt(const float* __restrict__ a, __bf16* __restrict__ Lb) {
    __shared__ float s[64][65];
    int bi = blockIdx.x * 64;
    int bj = blockIdx.y * 64;
    int t = threadIdx.x;
    for (int q = t; q < 64 * 64; q += 256) {
        int r = q >> 6, c = q & 63;
        int jj = bj + r, ii = bi + c;
        s[r][c] = (jj < NN && ii < NN) ? a[jj * NN + ii] : 0.f;
    }
    __syncthreads();
    for (int q = t; q < 64 * 64; q += 256) {
        int r = q >> 6, c = q & 63;
        int ii = bi + r, jj = bj + c;
        if (ii < NN && jj < NN)
            Lb[(size_t)ii * KP + jj] = (__bf16)(0.5f * (s[c][r] + (ii == jj ? 1.0f : 0.0f)));
    }
}

// ---------------- one-time weight prep ----------------
__global__ void k_prep(const float* __restrict__ wih, const float* __restrict__ whh,
                       const float* __restrict__ proj_w, const float* __restrict__ ow1,
                       const float* __restrict__ ow2, const float* __restrict__ gc1_w,
                       const float* __restrict__ gc2_w,
                       __bf16* __restrict__ WihB, __bf16* __restrict__ WhhB,
                       __bf16* __restrict__ projB, __bf16* __restrict__ w1B,
                       __bf16* __restrict__ w2B, __bf16* __restrict__ W1t,
                       __bf16* __restrict__ W2t) {
    int idx = blockIdx.x * 256 + threadIdx.x;
    if (idx < 49152) { WihB[idx] = (__bf16)wih[idx]; return; }
    idx -= 49152;
    if (idx < 49152) { WhhB[idx] = (__bf16)whh[idx]; return; }
    idx -= 49152;
    if (idx < 16384) { projB[idx] = (__bf16)proj_w[idx]; return; }
    idx -= 16384;
    if (idx < 32768) { w1B[idx] = (__bf16)ow1[idx]; return; }
    idx -= 32768;
    if (idx < 32768) { w2B[idx] = (__bf16)ow2[idx]; return; }
    idx -= 32768;
    if (idx < 2 * 256 * CP2) {
        int l = idx / (256 * CP2); int r = idx % (256 * CP2); int o = r / CP2, c = r % CP2;
        W1t[idx] = (c < CC) ? (__bf16)gc1_w[((size_t)l * CC + c) * 256 + o] : (__bf16)0.f;
        return;
    }
    idx -= 2 * 256 * CP2;
    if (idx < 2 * 128 * CP2) {
        int l = idx / (128 * CP2); int r = idx % (128 * CP2); int o = r / CP2, c = r % CP2;
        W2t[idx] = (c < CC) ? (__bf16)gc2_w[((size_t)l * CC + c) * 128 + o] : (__bf16)0.f;
    }
}

// Gfull0 row0 = x at t=0
__global__ void k_prep_x(const float* __restrict__ inp, __bf16* __restrict__ G0) {
    int idx = blockIdx.x * 256 + threadIdx.x;
    if (idx >= BB * 1024) return;
    int b = idx >> 10, k = idx & 1023;
    G0[(size_t)b * GR * KP + k] = (k < NN) ? (__bf16)inp[(size_t)b * TT * NN + k] : (__bf16)0.f;
}

// ---------------- fused graph-conv + weight matmul + epilogue (+ GRU when STORE) -------
// 512 threads = 8 waves. Stage-1: wm = m-half (16 rows), wcg = 4 c-groups {3,2,2,2}.
// K=1024 in 16 steps of 64; 3-buffer pipeline, counted vmcnt (nld per wave), XOR-swizzle.
// Stage-2: MODE0 all 8 waves x 2 o-frags; MODE1 all 8 waves x 1. Epilogues verified r10/r12.
// State slimming (r13): h, u bf16; GRU state only in Hb (bf16, blend reads LDS copy).
#define GL16(SRC, DSTOFF)                                                            \
    __builtin_amdgcn_global_load_lds(                                                \
        (const __attribute__((address_space(1))) unsigned int*)(SRC),                \
        (__attribute__((address_space(3))) unsigned int*)(smem + (DSTOFF)), 16, 0, 0)

template<int MODE, int STORE>
__global__ __launch_bounds__(512) void k_fused(
    const __bf16* __restrict__ Lb, const __bf16* __restrict__ Gf,
    const __bf16* __restrict__ Wt, const float* __restrict__ bias,
    __bf16* __restrict__ GB, __bf16* __restrict__ u, __bf16* __restrict__ h,
    const float* __restrict__ x_in, int xstride,
    const float* __restrict__ res_w, const float* __restrict__ res_b,
    const float* __restrict__ ln_g, const float* __restrict__ ln_b,
    float* __restrict__ x_out, __bf16* __restrict__ Gnext,
    __bf16* __restrict__ GhSelf,
    __bf16* __restrict__ Hb,
    const __bf16* __restrict__ WihB, const __bf16* __restrict__ WhhB,
    const float* __restrict__ bih, const float* __restrict__ bhh,
    const float* __restrict__ inp, __bf16* __restrict__ xnextG, int tnext)
{
    __shared__ __align__(16) char smem[SMEMB];
    __bf16* sP   = (__bf16*)smem;                   // [32][168] overlay @0
    __bf16* sGT  = (__bf16*)(smem + OFF_SGT);       // MODE0 [256][40]
    __bf16* sT   = (__bf16*)(smem + OFF_SGT);       // MODE1 [128][40]
    __bf16* sO   = (__bf16*)(smem + OFF_SO);        // MODE1 [32][136]
    float*  sScal= (float*)(smem + OFF_SCAL);
    float*  sSt  = (float*)(smem + OFF_SST);        // [2][8][32]

    int tid = threadIdx.x;
    int wg = blockIdx.x;
    int b = wg & 15;                 // wg%8 == b%8 -> XCD locality
    int m0 = (wg >> 4) * 32;
    int wave = tid >> 6, lane = tid & 63;
    int lr = lane & 15, lk = lane >> 4;
    int wm = wave >> 2;              // m-half (16 rows)
    int wcg = wave & 3;              // c-group
    int cgbase = (wcg == 0) ? 0 : (wcg * 2 + 1) * 16;   // {0,48,80,112}
    int NC = (wcg == 0) ? 3 : 2;

    if (MODE == 0) {
        if (tid < 256) sScal[tid] = bias[tid];
    } else if (tid < 128) {
        sScal[tid] = bias[tid];
        sScal[128 + tid] = res_w[tid];
        sScal[256 + tid] = res_b[tid];
        sScal[384 + tid] = ln_g[tid];
        sScal[512 + tid] = ln_b[tid];
    }

    size_t srowOff = (size_t)b * GR * KP;
    int rIn = lane >> 3;
    int cswz = ((lane & 7) ^ rIn) * 8;   // pre-swizzled source col (elems)

    // staging: 22 chunks of 1KB (4 L + 18 G); wave w -> {w, w+8, w+16 if <22}.
    int nld = (wave < 6) ? 3 : 2;
    const __bf16* psrc[3];
    int pdst[3];
#pragma unroll
    for (int q = 0; q < 3; q++) {
        int c = wave + q * 8;
        if (c < 22) {
            psrc[q] = (c < 4)
                ? Lb + (size_t)(m0 + c * 8 + rIn) * KP + cswz
                : Gf + srowOff + (size_t)((c - 4) * 8 + rIn) * KP + cswz;
            pdst[q] = c * 1024;
        } else { psrc[q] = nullptr; pdst[q] = 0; }
    }

#define STAGE(BUF, IT) {                                                     \
    _Pragma("unroll")                                                        \
    for (int q = 0; q < 3; q++)                                              \
        if (wave + q * 8 < 22)                                               \
            GL16(psrc[q] + (IT) * 64, (BUF) * BUFSZ + pdst[q]); }

    f32x4 acc[3];
#pragma unroll
    for (int j = 0; j < 3; j++) acc[j] = (f32x4){0.f, 0.f, 0.f, 0.f};

    STAGE(0, 0);
    __syncthreads();                 // drains tile0 + sScal
    STAGE(1, 1);
    int bc = 0;
    for (int it = 0; it < 16; ++it) {
        if (it == 15) asm volatile("s_waitcnt vmcnt(0)" ::: "memory");
        else if (nld == 3) asm volatile("s_waitcnt vmcnt(3)" ::: "memory");
        else               asm volatile("s_waitcnt vmcnt(2)" ::: "memory");
        __builtin_amdgcn_s_barrier();
        __builtin_amdgcn_sched_barrier(0);
        const char* bp = smem + bc * BUFSZ;
#pragma unroll
        for (int ks = 0; ks < 2; ks++) {
            int kb = (ks * 64 + lk * 16) ^ ((lr & 7) << 4);
            int chA = wm * 2 + (lr >> 3);
            bf16x8 af = *(const bf16x8*)(bp + chA * 1024 + (lr & 7) * 128 + kb);
#pragma unroll
            for (int cf = 0; cf < 3; cf++) {
                if (cf < NC) {
                    int chB = 4 + (cgbase >> 3) + cf * 2 + (lr >> 3);
                    bf16x8 bfr = *(const bf16x8*)(bp + chB * 1024 + (lr & 7) * 128 + kb);
                    acc[cf] = MFMA16(af, bfr, acc[cf]);
                }
            }
        }
        if (it < 14) { int bs = (it + 2) % 3; STAGE(bs, it + 2); }
        bc = (bc == 2) ? 0 : bc + 1;
    }
    __syncthreads();
#undef STAGE

    // P -> sP bf16 (overlay @0; staging dead)
#pragma unroll
    for (int cf = 0; cf < 3; cf++) {
        if (cf < NC) {
#pragma unroll
            for (int i = 0; i < 4; i++)
                sP[(wm * 16 + lk * 4 + i) * SPS + cgbase + cf * 16 + lr] = (__bf16)acc[cf][i];
        }
    }
    for (int q = tid; q < 32 * 16; q += 512) sP[(q >> 4) * SPS + 144 + (q & 15)] = (__bf16)0.f;
    __syncthreads();

    // Stage 2: MODE0 -> 8 waves x 2 o-frags (o0=wave*32); MODE1 -> 8 waves x 1 (o0=wave*16).
    constexpr int NOF = (MODE == 0) ? 2 : 1;
    int o0 = wave * NOF * 16;
    int j = o0 + lr;                 // MODE1 j in [0,128)
    f32x4 accs[2][NOF];
#pragma unroll
    for (int i = 0; i < 2; i++)
#pragma unroll
        for (int jj = 0; jj < NOF; jj++) accs[i][jj] = (f32x4){0.f, 0.f, 0.f, 0.f};
#pragma unroll
    for (int kk2 = 0; kk2 < CP2; kk2 += 32) {
        bf16x8 pa[2];
#pragma unroll
        for (int mf2 = 0; mf2 < 2; mf2++)
            pa[mf2] = *(const bf16x8*)&sP[(mf2 * 16 + lr) * SPS + kk2 + lk * 8];
#pragma unroll
        for (int of = 0; of < NOF; of++) {
            bf16x8 wb = *(const bf16x8*)&Wt[(size_t)(o0 + of * 16 + lr) * CP2 + kk2 + lk * 8];
#pragma unroll
            for (int mf2 = 0; mf2 < 2; mf2++)
                accs[mf2][of] = MFMA16(pa[mf2], wb, accs[mf2][of]);
        }
    }

    if (MODE == 0) {
        if (tid < 4)
            *(bf16x8*)&GB[srowOff + m0 + tid * 8] = *(const bf16x8*)&Gf[srowOff + m0 + tid * 8];
        bool clean = (m0 + 32 <= 500);
        if (clean) {
#pragma unroll
            for (int of = 0; of < NOF; of++) {
                int o = o0 + of * 16 + lr;
                float bv = sScal[o];
#pragma unroll
                for (int mf2 = 0; mf2 < 2; mf2++)
#pragma unroll
                    for (int i = 0; i < 4; i++)
                        sGT[o * 40 + mf2 * 16 + lk * 4 + i] = (__bf16)sigmoidf_(accs[mf2][of][i] + bv);
            }
            __syncthreads();
            for (int q = tid; q < 128 * 8; q += 512) {
                int jj = q >> 3;
                int rnc = (q & 7) * 4;
                size_t gidx = srowOff + (size_t)(1 + jj) * KP + 2 * m0 + rnc * 2;
                bf16x8 hv = *(const bf16x8*)&Gf[gidx];
                bf16x8 rv;
#pragma unroll
                for (int e = 0; e < 8; e++) {
                    int rnl = rnc + (e >> 1);
                    int hi = e & 1;
                    float g = (float)sGT[(hi * 128 + jj) * 40 + rnl];
                    rv[e] = (__bf16)(g * (float)hv[e]);
                }
                *(bf16x8*)&GB[gidx] = rv;
            }
        } else {
#pragma unroll
            for (int of = 0; of < NOF; of++) {
                int o = o0 + of * 16 + lr;
                int jo = o & 127, hi = o >> 7;
                float bv = sScal[o];
#pragma unroll
                for (int mf2 = 0; mf2 < 2; mf2++)
#pragma unroll
                    for (int i = 0; i < 4; i++) {
                        int m = m0 + mf2 * 16 + lk * 4 + i;
                        if (m >= NN) continue;
                        float g = sigmoidf_(accs[mf2][of][i] + bv);
                        if (m < 500) {
                            size_t gi = srowOff + (size_t)(1 + jo) * KP + 2 * m + hi;
                            GB[gi] = (__bf16)(g * (float)Gf[gi]);
                        } else {
                            u[((size_t)b * NN + 2 * (m - 500) + hi) * HH + jo] = (__bf16)g;
                        }
                    }
            }
        }
    } else {
        float hnv[2][4];
        float mu_[2][4], rs_[2][4];
        float xs_[2][4];
        {
            float s_[2][4], ss_[2][4];
#pragma unroll
            for (int a = 0; a < 2; a++)
#pragma unroll
                for (int i = 0; i < 4; i++) { s_[a][i] = 0.f; ss_[a][i] = 0.f; }
            float b2v = sScal[j], rwv = sScal[128 + j], rbv = sScal[256 + j];
#pragma unroll
            for (int mf2 = 0; mf2 < 2; mf2++) {
#pragma unroll
                for (int i = 0; i < 4; i++) {
                    int m = m0 + mf2 * 16 + lk * 4 + i;
                    int msafe = (m < NN) ? m : (NN - 1);
                    size_t ri = ((size_t)b * NN + msafe) * HH + j;
                    float cv = tanhf(accs[mf2][0][i] + b2v);
                    float uu = (float)u[ri];
                    float hv = (float)h[ri];
                    float hn = uu * hv + (1.f - uu) * cv;
                    if (m < NN) h[ri] = (__bf16)hn;
                    hnv[mf2][i] = hn;
                    float xv = (m < NN) ? x_in[(size_t)b * xstride + m] : 0.f;
                    float y = hn + xv * rwv + rbv;
                    accs[mf2][0][i] = y;
                    s_[mf2][i] += y; ss_[mf2][i] += y * y;
                }
            }
#pragma unroll
            for (int msk = 1; msk < 16; msk <<= 1)
#pragma unroll
                for (int a = 0; a < 2; a++)
#pragma unroll
                    for (int i = 0; i < 4; i++) {
                        s_[a][i] += __shfl_xor(s_[a][i], msk);
                        ss_[a][i] += __shfl_xor(ss_[a][i], msk);
                    }
            if (lr == 0) {
#pragma unroll
                for (int a = 0; a < 2; a++)
#pragma unroll
                    for (int i = 0; i < 4; i++) {
                        int ml = a * 16 + lk * 4 + i;
                        sSt[wave * 32 + ml] = s_[a][i];
                        sSt[256 + wave * 32 + ml] = ss_[a][i];
                    }
            }
        }
        __syncthreads();
        {
#pragma unroll
            for (int a = 0; a < 2; a++)
#pragma unroll
                for (int i = 0; i < 4; i++) {
                    int ml = a * 16 + lk * 4 + i;
                    float S = 0.f, SS = 0.f;
#pragma unroll
                    for (int w = 0; w < 8; w++) { S += sSt[w * 32 + ml]; SS += sSt[256 + w * 32 + ml]; }
                    float mu = S * (1.f / 128.f);
                    float var = SS * (1.f / 128.f) - mu * mu;
                    mu_[a][i] = mu;
                    rs_[a][i] = rsqrtf(var + 1e-5f);
                }
            float lg = sScal[384 + j], lb2 = sScal[512 + j];
#pragma unroll
            for (int mf2 = 0; mf2 < 2; mf2++)
#pragma unroll
                for (int i = 0; i < 4; i++) {
                    float ov = (accs[mf2][0][i] - mu_[mf2][i]) * rs_[mf2][i] * lg + lb2;
                    accs[mf2][0][i] = ov;
                    xs_[mf2][i] = ov;
                }
#pragma unroll
            for (int msk = 1; msk < 16; msk <<= 1)
#pragma unroll
                for (int a = 0; a < 2; a++)
#pragma unroll
                    for (int i = 0; i < 4; i++) xs_[a][i] += __shfl_xor(xs_[a][i], msk);
        }
        __syncthreads();
        if (lr == 0) {
#pragma unroll
            for (int a = 0; a < 2; a++)
#pragma unroll
                for (int i = 0; i < 4; i++)
                    sSt[wave * 32 + a * 16 + lk * 4 + i] = xs_[a][i];
        }
        __syncthreads();
        if (wave == 0 && lr == 0) {
#pragma unroll
            for (int a = 0; a < 2; a++)
#pragma unroll
                for (int i = 0; i < 4; i++) {
                    int ml = a * 16 + lk * 4 + i;
                    int m = m0 + ml;
                    if (m < NN) {
                        float S = 0.f;
#pragma unroll
                        for (int w = 0; w < 8; w++) S += sSt[w * 32 + ml];
                        float xv = S * (1.f / 128.f);
                        if (x_out) x_out[(size_t)b * NN + m] = xv;
                        if (Gnext) Gnext[(size_t)b * GR * KP + m] = (__bf16)xv;
                    }
                }
        }
        {
#pragma unroll
            for (int mf2 = 0; mf2 < 2; mf2++)
#pragma unroll
                for (int i = 0; i < 4; i++)
                    sT[j * 40 + mf2 * 16 + lk * 4 + i] = (__bf16)hnv[mf2][i];
            if (STORE) {
#pragma unroll
                for (int mf2 = 0; mf2 < 2; mf2++)
#pragma unroll
                    for (int i = 0; i < 4; i++)
                        sO[(mf2 * 16 + lk * 4 + i) * 136 + j] = (__bf16)accs[mf2][0][i];
            }
        }
        if (STORE) {
            // stage previous-h GRU state (Hb) into LDS once (32 rows x 128 cols bf16)
            int row = tid >> 4, c8 = (tid & 15) * 8;
            int m = m0 + row;
            size_t hrow = (size_t)b * NN + ((m < NN) ? m : (NN - 1));
            *(bf16x8*)(smem + OFF_SHB + (row * 136 + c8) * 2) =
                *(const bf16x8*)&Hb[hrow * HH + c8];
        }
        __syncthreads();
        {
            int q = tid;   // 128 j x 4 chunks = 512 = blockDim
            int jj = q >> 2, mc = (q & 3) * 8;
            if (m0 + mc < NN)
                *(bf16x8*)&GhSelf[srowOff + (size_t)(1 + jj) * KP + m0 + mc] =
                    *(const bf16x8*)&sT[jj * 40 + mc];
        }
        if (STORE) {
            // ---- fused GRU step (wave-local j-slice: rows {j, 128+j, 256+j}) ----
            {
                float br  = bih[j] + bhh[j];
                float bz  = bih[128 + j] + bhh[128 + j];
                float bni = bih[256 + j], bnh = bhh[256 + j];
                const __bf16* wir = WihB + (size_t)j * HH;
                const __bf16* whr = WhhB + (size_t)j * HH;
                const __bf16* wiz = WihB + (size_t)(128 + j) * HH;
                const __bf16* whz = WhhB + (size_t)(128 + j) * HH;
                const __bf16* win = WihB + (size_t)(256 + j) * HH;
                const __bf16* whn = WhhB + (size_t)(256 + j) * HH;
#pragma unroll
                for (int mf = 0; mf < 2; mf++) {
                    f32x4 gr = (f32x4){0.f,0.f,0.f,0.f}, gz = gr, gni = gr, gnh = gr;
#pragma unroll
                    for (int kk = 0; kk < 128; kk += 32) {
                        bf16x8 xa = *(const bf16x8*)&sO[(mf * 16 + lr) * 136 + kk + lk * 8];
                        bf16x8 ha = *(const bf16x8*)(smem + OFF_SHB + ((mf * 16 + lr) * 136 + kk + lk * 8) * 2);
                        gr  = MFMA16(xa, *(const bf16x8*)(wir + kk + lk * 8), gr);
                        gr  = MFMA16(ha, *(const bf16x8*)(whr + kk + lk * 8), gr);
                        gz  = MFMA16(xa, *(const bf16x8*)(wiz + kk + lk * 8), gz);
                        gz  = MFMA16(ha, *(const bf16x8*)(whz + kk + lk * 8), gz);
                        gni = MFMA16(xa, *(const bf16x8*)(win + kk + lk * 8), gni);
                        gnh = MFMA16(ha, *(const bf16x8*)(whn + kk + lk * 8), gnh);
                    }
#pragma unroll
                    for (int i = 0; i < 4; i++) {
                        int m = m0 + mf * 16 + lk * 4 + i;
                        if (m >= NN) continue;
                        size_t ri = ((size_t)b * NN + m) * HH + j;
                        // previous GRU state from the LDS copy (same value as Hb[ri])
                        float hv = (float)*(const __bf16*)(smem + OFF_SHB +
                                      ((mf * 16 + lk * 4 + i) * 136 + j) * 2);
                        float rg = sigmoidf_(gr[i] + br);
                        float zg = sigmoidf_(gz[i] + bz);
                        float ng = tanhf(gni[i] + bni + rg * (gnh[i] + bnh));
                        float hp = (1.f - zg) * ng + zg * hv;
                        Hb[ri] = (__bf16)hp;
                    }
                }
            }
            if (tid < 32 && tnext < TT) {
                int n = m0 + tid;
                if (n < NN)
                    xnextG[srowOff + n] = (__bf16)inp[(size_t)b * TT * NN + tnext * NN + n];
            }
        }
    }
}
#undef GL16

// ---------------- head: proj -> relu MLP -> out, MFMA ----------------
__global__ __launch_bounds__(256) void k_head_mfma(const __bf16* __restrict__ Hb,
                                                   const __bf16* __restrict__ projB,
                                                   const float* __restrict__ pb,
                                                   const __bf16* __restrict__ w1B,
                                                   const float* __restrict__ b1,
                                                   const __bf16* __restrict__ w2B,
                                                   const float* __restrict__ b2,
                                                   float* __restrict__ out) {
    __shared__ __align__(16) __bf16 sH1[64 * 136];
    __shared__ __align__(16) __bf16 sH2[64 * 264];
    int tid = threadIdx.x;
    int r0 = blockIdx.x * 64;
    int wv = tid >> 6, lane = tid & 63;
    int lr = lane & 15, lk = lane >> 4;
    int arow = r0 + wv * 16 + lr;

    f32x4 a1[8];
#pragma unroll
    for (int i = 0; i < 8; i++) a1[i] = (f32x4){0.f, 0.f, 0.f, 0.f};
#pragma unroll
    for (int kk = 0; kk < 128; kk += 32) {
        bf16x8 xa = *(const bf16x8*)&Hb[(size_t)arow * HH + kk + lk * 8];
#pragma unroll
        for (int f = 0; f < 8; f++) {
            bf16x8 wb = *(const bf16x8*)&projB[(size_t)(f * 16 + lr) * HH + kk + lk * 8];
            a1[f] = MFMA16(xa, wb, a1[f]);
        }
    }
#pragma unroll
    for (int f = 0; f < 8; f++) {
        int j = f * 16 + lr;
        float bv = pb[j];
#pragma unroll
        for (int i = 0; i < 4; i++)
            sH1[(wv * 16 + lk * 4 + i) * 136 + j] = (__bf16)(a1[f][i] + bv);
    }
    __syncthreads();

    f32x4 a2[16];
#pragma unroll
    for (int i = 0; i < 16; i++) a2[i] = (f32x4){0.f, 0.f, 0.f, 0.f};
#pragma unroll
    for (int kk = 0; kk < 128; kk += 32) {
        bf16x8 pa = *(const bf16x8*)&sH1[(wv * 16 + lr) * 136 + kk + lk * 8];
#pragma unroll
        for (int f = 0; f < 16; f++) {
            bf16x8 wb = *(const bf16x8*)&w1B[(size_t)(f * 16 + lr) * HH + kk + lk * 8];
            a2[f] = MFMA16(pa, wb, a2[f]);
        }
    }
    __syncthreads();
#pragma unroll
    for (int f = 0; f < 16; f++) {
        int o = f * 16 + lr;
        float bv = b1[o];
#pragma unroll
        for (int i = 0; i < 4; i++)
            sH2[(wv * 16 + lk * 4 + i) * 264 + o] = (__bf16)fmaxf(a2[f][i] + bv, 0.f);
    }
    __syncthreads();

    f32x4 a3[8];
#pragma unroll
    for (int i = 0; i < 8; i++) a3[i] = (f32x4){0.f, 0.f, 0.f, 0.f};
#pragma unroll
    for (int kk = 0; kk < 256; kk += 32) {
        bf16x8 pa = *(const bf16x8*)&sH2[(wv * 16 + lr) * 264 + kk + lk * 8];
#pragma unroll
        for (int f = 0; f < 8; f++) {
            bf16x8 wb = *(const bf16x8*)&w2B[(size_t)(f * 16 + lr) * 256 + kk + lk * 8];
            a3[f] = MFMA16(pa, wb, a3[f]);
        }
    }
#pragma unroll
    for (int f = 0; f < 8; f++) {
        int j = f * 16 + lr;
        float bv = b2[j];
#pragma unroll
        for (int i = 0; i < 4; i++)
            out[(size_t)(r0 + wv * 16 + lk * 4 + i) * HH + j] = a3[f][i] + bv;
    }
}

extern "C" void kernel_launch(void* const* d_in, const int* in_sizes, int n_in,
                              void* d_out, int out_size, void* d_ws, size_t ws_size,
                              hipStream_t stream) {
    const float* inp    = (const float*)d_in[0];
    const float* adj    = (const float*)d_in[1];
    const float* gc1_w  = (const float*)d_in[2];
    const float* gc1_b  = (const float*)d_in[3];
    const float* gc2_w  = (const float*)d_in[4];
    const float* gc2_b  = (const float*)d_in[5];
    const float* ln_g   = (const float*)d_in[6];
    const float* ln_b   = (const float*)d_in[7];
    const float* res_w  = (const float*)d_in[8];
    const float* res_b  = (const float*)d_in[9];
    const float* wih    = (const float*)d_in[10];
    const float* whh    = (const float*)d_in[11];
    const float* bih    = (const float*)d_in[12];
    const float* bhh    = (const float*)d_in[13];
    const float* proj_w = (const float*)d_in[14];
    const float* proj_b = (const float*)d_in[15];
    const float* ow1    = (const float*)d_in[16];
    const float* ob1    = (const float*)d_in[17];
    const float* ow2    = (const float*)d_in[18];
    const float* ob2    = (const float*)d_in[19];
    float* out = (float*)d_out;

    char* ws = (char*)d_ws;
    size_t off = 0;
    __bf16* Lb     = (__bf16*)(ws + off); off += (size_t)KP * KP * 2;          // 2 MB
    __bf16* Gfull0 = (__bf16*)(ws + off); off += (size_t)BB * GR * KP * 2;     // 5 MB
    __bf16* Gfull1 = (__bf16*)(ws + off); off += (size_t)BB * GR * KP * 2;
    __bf16* GfullB = (__bf16*)(ws + off); off += (size_t)BB * GR * KP * 2;
    size_t zgrp1 = off;
    __bf16* h0  = (__bf16*)(ws + off); off += (size_t)NROW * HH * 2;           // bf16 state
    __bf16* h1  = (__bf16*)(ws + off); off += (size_t)NROW * HH * 2;
    __bf16* Hb  = (__bf16*)(ws + off); off += (size_t)NROW * HH * 2;
    size_t zgrp2 = off;
    __bf16* u   = (__bf16*)(ws + off); off += (size_t)NROW * HH * 2;
    float* xB   = (float*)(ws + off);  off += NROW * 4;
    __bf16* W1t = (__bf16*)(ws + off); off += (size_t)2 * 256 * CP2 * 2;
    __bf16* W2t = (__bf16*)(ws + off); off += (size_t)2 * 128 * CP2 * 2;
    __bf16* WihB= (__bf16*)(ws + off); off += 49152 * 2;
    __bf16* WhhB= (__bf16*)(ws + off); off += 49152 * 2;
    __bf16* projB=(__bf16*)(ws + off); off += 16384 * 2;
    __bf16* w1B = (__bf16*)(ws + off); off += 32768 * 2;
    __bf16* w2B = (__bf16*)(ws + off); off += 32768 * 2;
    float* a_sm = (float*)u;   // overlay: softmax scratch (4MB) used before u's first write

    hipMemsetAsync(Lb, 0, zgrp1, stream);                     // Lb + Gfull0/1/B
    hipMemsetAsync(h0, 0, zgrp2 - zgrp1, stream);             // h0, h1, Hb (bf16)

    k_softmax<<<NN, 256, 0, stream>>>(adj, a_sm);
    k_build_Lt<<<dim3(16, 16), 256, 0, stream>>>(a_sm, Lb);
    k_prep<<<1184, 256, 0, stream>>>(wih, whh, proj_w, ow1, ow2, gc1_w, gc2_w,
                                     WihB, WhhB, projB, w1B, w2B, W1t, W2t);
    k_prep_x<<<64, 256, 0, stream>>>(inp, Gfull0);

    for (int t = 0; t < TT; t++) {
        const float* xs0 = inp + (size_t)t * NN;
        // layer 0
        k_fused<0, 0><<<512, 512, 0, stream>>>(Lb, Gfull0, W1t, gc1_b, GfullB, u,
            nullptr, nullptr, 0, nullptr, nullptr, nullptr, nullptr,
            nullptr, nullptr, nullptr,
            nullptr, nullptr, nullptr, nullptr, nullptr, nullptr, nullptr, 0);
        k_fused<1, 0><<<512, 512, 0, stream>>>(Lb, GfullB, W2t, gc2_b, nullptr, u, h0,
            xs0, TT * NN, res_w, res_b, ln_g, ln_b,
            xB, Gfull1, Gfull0,
            nullptr, nullptr, nullptr, nullptr, nullptr, nullptr, nullptr, 0);
        // layer 1
        k_fused<0, 0><<<512, 512, 0, stream>>>(Lb, Gfull1, W1t + 256 * CP2, gc1_b + 256, GfullB, u,
            nullptr, nullptr, 0, nullptr, nullptr, nullptr, nullptr,
            nullptr, nullptr, nullptr,
            nullptr, nullptr, nullptr, nullptr, nullptr, nullptr, nullptr, 0);
        k_fused<1, 1><<<512, 512, 0, stream>>>(Lb, GfullB, W2t + 128 * CP2, gc2_b + 128, nullptr, u, h1,
            xB, NN, res_w, res_b, ln_g + 128, ln_b + 128,
            nullptr, nullptr, Gfull1,
            Hb, WihB, WhhB, bih, bhh, inp, Gfull0, t + 1);
    }
    k_head_mfma<<<250, 256, 0, stream>>>(Hb, projB, proj_b, w1B, ob1, w2B, ob2, out);
}